// Round 1
// baseline (1430.701 us; speedup 1.0000x reference)
//
#include <hip/hip_runtime.h>
#include <math.h>

#define H 64
#define IN_DIM 128
#define NRELS 8

// monotonic encoding of f32 into uint for atomicMax
__device__ inline unsigned enc_f32(float f) {
  unsigned b = __float_as_uint(f);
  return (b & 0x80000000u) ? ~b : (b | 0x80000000u);
}
__device__ inline float dec_f32(unsigned u) {
  return __uint_as_float((u & 0x80000000u) ? (u & 0x7FFFFFFFu) : ~u);
}

// h0 = relu(x @ W_in + b_in).  Block = 256 thr = 4 nodes x 64 feats.
__global__ __launch_bounds__(256) void k_input(const float* __restrict__ x,
    const float* __restrict__ W_in, const float* __restrict__ b_in,
    float* __restrict__ h, int N) {
  __shared__ float Ws[IN_DIM * H];   // 32 KB
  __shared__ float xs[4][IN_DIM];    // 2 KB
  for (int i = threadIdx.x; i < IN_DIM * H; i += 256) Ws[i] = W_in[i];
  int nodeBase = blockIdx.x * 4;
  int wid = threadIdx.x >> 6, lane = threadIdx.x & 63;
  for (int i = threadIdx.x; i < 4 * IN_DIM; i += 256) {
    int nn = nodeBase + i / IN_DIM;
    xs[i / IN_DIM][i % IN_DIM] = (nn < N) ? x[(size_t)nn * IN_DIM + (i % IN_DIM)] : 0.f;
  }
  __syncthreads();
  int n = nodeBase + wid;
  if (n >= N) return;
  float acc = 0.f;
  #pragma unroll 8
  for (int k = 0; k < IN_DIM; ++k)
    acc = fmaf(xs[wid][k], Ws[k * H + lane], acc);
  acc += b_in[lane];
  h[(size_t)n * H + lane] = fmaxf(acc, 0.f);
}

// hw = h @ Wmsg ; esrc = hw . a_src ; edst = hw . a_dst   (wave per node)
__global__ __launch_bounds__(256) void k_node(const float* __restrict__ h,
    const float* __restrict__ Wmsg, const float* __restrict__ att,
    float* __restrict__ hw, float* __restrict__ esrc, float* __restrict__ edst,
    int N) {
  __shared__ float Ws[H * H];   // 16 KB
  __shared__ float hs[4][H];    // 1 KB
  for (int i = threadIdx.x; i < H * H; i += 256) Ws[i] = Wmsg[i];
  int nodeBase = blockIdx.x * 4;
  int wid = threadIdx.x >> 6, lane = threadIdx.x & 63;
  for (int i = threadIdx.x; i < 4 * H; i += 256) {
    int nn = nodeBase + (i >> 6);
    hs[i >> 6][i & 63] = (nn < N) ? h[(size_t)nn * H + (i & 63)] : 0.f;
  }
  __syncthreads();
  int n = nodeBase + wid;
  if (n >= N) return;
  float acc = 0.f;
  #pragma unroll 8
  for (int k = 0; k < H; ++k)
    acc = fmaf(hs[wid][k], Ws[k * H + lane], acc);
  hw[(size_t)n * H + lane] = acc;
  float vd = acc * att[lane];        // a_dst
  float vs = acc * att[H + lane];    // a_src
  #pragma unroll
  for (int o = 32; o >= 1; o >>= 1) {
    vd += __shfl_xor(vd, o);
    vs += __shfl_xor(vs, o);
  }
  if (lane == 0) { edst[n] = vd; esrc[n] = vs; }
}

// erel[r] = (rel_emb[r] @ W_relproj) . a_rel   — 1 block, 512 thr (wave per rel)
__global__ void k_rel(const float* __restrict__ rel_emb,
    const float* __restrict__ Wrp, const float* __restrict__ att,
    float* __restrict__ erel) {
  int r = threadIdx.x >> 6, lane = threadIdx.x & 63;
  float acc = 0.f;
  #pragma unroll
  for (int k = 0; k < 16; ++k)
    acc = fmaf(rel_emb[r * 16 + k], Wrp[k * H + lane], acc);
  float v = acc * att[2 * H + lane];
  #pragma unroll
  for (int o = 32; o >= 1; o >>= 1) v += __shfl_xor(v, o);
  if (lane == 0) erel[r] = v;
}

// pass 1: per-edge logit + segment max via encoded atomicMax
__global__ __launch_bounds__(256) void k_edge1(const int* __restrict__ ei,
    const int* __restrict__ et, const float* __restrict__ ea,
    const float* __restrict__ esrc, const float* __restrict__ edst,
    const float* __restrict__ erel,
    float* __restrict__ ebuf, unsigned* __restrict__ menc, int E) {
  __shared__ float er[NRELS];
  if (threadIdx.x < NRELS) er[threadIdx.x] = erel[threadIdx.x];
  __syncthreads();
  int i = blockIdx.x * 256 + threadIdx.x;
  if (i >= E) return;
  int s = ei[i], d = ei[E + i];
  int t = et[i]; t = t < 0 ? 0 : (t > NRELS - 1 ? NRELS - 1 : t);
  float e = edst[d] + esrc[s] + er[t];
  e = e > 0.f ? e : 0.2f * e;                  // leaky_relu 0.2
  e += 0.1f * logf(fmaxf(ea[i], 1e-6f));      // conf term
  ebuf[i] = e;
  atomicMax(&menc[d], enc_f32(e));
}

// pass 2: wave per edge; acc[dst] += hw[src]*ex ; s[dst] += ex
__global__ __launch_bounds__(256) void k_edge2(const int* __restrict__ ei,
    const float* __restrict__ ebuf, const unsigned* __restrict__ menc,
    const float* __restrict__ hw,
    float* __restrict__ acc, float* __restrict__ ssum, int E) {
  int w = (blockIdx.x * 256 + threadIdx.x) >> 6;
  int lane = threadIdx.x & 63;
  if (w >= E) return;
  int s = ei[w], d = ei[E + w];
  float ex = __expf(ebuf[w] - dec_f32(menc[d]));
  float v = hw[(size_t)s * H + lane] * ex;
  atomicAdd(&acc[(size_t)d * H + lane], v);
  if (lane == 0) atomicAdd(&ssum[d], ex);
}

// finalize: out = acc/s + bias ; h = layernorm(h + relu(out))  (wave per node)
__global__ __launch_bounds__(256) void k_fin(const float* __restrict__ h,
    const float* __restrict__ acc, const float* __restrict__ ssum,
    const float* __restrict__ bias, const float* __restrict__ ln_g,
    const float* __restrict__ ln_b, float* __restrict__ hout, int N) {
  int w = (blockIdx.x * 256 + threadIdx.x) >> 6;
  int lane = threadIdx.x & 63;
  if (w >= N) return;
  float s = ssum[w];
  float o = (s > 0.f) ? acc[(size_t)w * H + lane] / s : 0.f;
  o += bias[lane];
  float v = h[(size_t)w * H + lane] + fmaxf(o, 0.f);
  float mu = v;
  #pragma unroll
  for (int off = 32; off >= 1; off >>= 1) mu += __shfl_xor(mu, off);
  mu *= (1.f / 64.f);
  float dv = v - mu;
  float var = dv * dv;
  #pragma unroll
  for (int off = 32; off >= 1; off >>= 1) var += __shfl_xor(var, off);
  var *= (1.f / 64.f);
  hout[(size_t)w * H + lane] = dv * rsqrtf(var + 1e-5f) * ln_g[lane] + ln_b[lane];
}

extern "C" void kernel_launch(void* const* d_in, const int* in_sizes, int n_in,
                              void* d_out, int out_size, void* d_ws, size_t ws_size,
                              hipStream_t stream) {
  const float* x       = (const float*)d_in[0];
  const float* W_in    = (const float*)d_in[1];
  const float* b_in    = (const float*)d_in[2];
  const float* W_msg   = (const float*)d_in[3];
  const float* rel_emb = (const float*)d_in[4];
  const float* W_rp    = (const float*)d_in[5];
  const float* att     = (const float*)d_in[6];
  const float* bias    = (const float*)d_in[7];
  const float* ln_g    = (const float*)d_in[8];
  const float* ln_b    = (const float*)d_in[9];
  const float* ea      = (const float*)d_in[10];
  const int*   ei      = (const int*)d_in[11];
  const int*   et      = (const int*)d_in[12];

  int N = in_sizes[0] / IN_DIM;
  int E = in_sizes[12];
  int L = in_sizes[7] / H;
  int R = in_sizes[5] / (L * H);   // 16

  float* ws   = (float*)d_ws;
  float* h    = ws;                         // N*H
  float* hw   = h    + (size_t)N * H;       // N*H
  float* accb = hw   + (size_t)N * H;       // N*H
  float* ebuf = accb + (size_t)N * H;       // E
  unsigned* menc = (unsigned*)(ebuf + E);   // N
  float* ssum = (float*)(menc + N);         // N
  float* esrc = ssum + N;                   // N
  float* edst = esrc + N;                   // N
  float* erel = edst + N;                   // NRELS

  int nb4 = (N + 3) / 4;
  k_input<<<nb4, 256, 0, stream>>>(x, W_in, b_in, h, N);

  for (int l = 0; l < L; ++l) {
    hipMemsetAsync(accb, 0, (size_t)N * H * sizeof(float), stream);
    hipMemsetAsync(menc, 0, (size_t)N * sizeof(unsigned), stream);
    hipMemsetAsync(ssum, 0, (size_t)N * sizeof(float), stream);
    k_node<<<nb4, 256, 0, stream>>>(h, W_msg + (size_t)l * H * H,
                                    att + (size_t)l * 3 * H, hw, esrc, edst, N);
    k_rel<<<1, 512, 0, stream>>>(rel_emb + (size_t)l * NRELS * R,
                                 W_rp + (size_t)l * R * H,
                                 att + (size_t)l * 3 * H, erel);
    k_edge1<<<(E + 255) / 256, 256, 0, stream>>>(ei, et, ea, esrc, edst, erel,
                                                 ebuf, menc, E);
    k_edge2<<<(E + 3) / 4, 256, 0, stream>>>(ei, ebuf, menc, hw, accb, ssum, E);
    float* hout = (l == L - 1) ? (float*)d_out : h;
    k_fin<<<(N + 3) / 4, 256, 0, stream>>>(h, accb, ssum, bias + (size_t)l * H,
                                           ln_g + (size_t)l * H,
                                           ln_b + (size_t)l * H, hout, N);
  }
}

// Round 3
// 849.962 us; speedup vs baseline: 1.6833x; 1.6833x over previous
//
#include <hip/hip_runtime.h>
#include <math.h>

#define H 64
#define IN_DIM 128
#define NRELS 8
#define SCAN_B 512

// h0 = relu(x @ W_in + b_in).  Block = 256 thr = 4 nodes x 64 feats.
__global__ __launch_bounds__(256) void k_input(const float* __restrict__ x,
    const float* __restrict__ W_in, const float* __restrict__ b_in,
    float* __restrict__ h, int N) {
  __shared__ float Ws[IN_DIM * H];   // 32 KB
  __shared__ float xs[4][IN_DIM];    // 2 KB
  for (int i = threadIdx.x; i < IN_DIM * H; i += 256) Ws[i] = W_in[i];
  int nodeBase = blockIdx.x * 4;
  int wid = threadIdx.x >> 6, lane = threadIdx.x & 63;
  for (int i = threadIdx.x; i < 4 * IN_DIM; i += 256) {
    int nn = nodeBase + i / IN_DIM;
    xs[i / IN_DIM][i % IN_DIM] = (nn < N) ? x[(size_t)nn * IN_DIM + (i % IN_DIM)] : 0.f;
  }
  __syncthreads();
  int n = nodeBase + wid;
  if (n >= N) return;
  float acc = 0.f;
  #pragma unroll 8
  for (int k = 0; k < IN_DIM; ++k)
    acc = fmaf(xs[wid][k], Ws[k * H + lane], acc);
  acc += b_in[lane];
  h[(size_t)n * H + lane] = fmaxf(acc, 0.f);
}

// ---- CSR build (once per call) ----
__global__ __launch_bounds__(256) void k_hist(const int* __restrict__ ei,
    int* __restrict__ deg, int E) {
  int i = blockIdx.x * 256 + threadIdx.x;
  if (i < E) atomicAdd(&deg[ei[E + i]], 1);
}

__global__ __launch_bounds__(SCAN_B) void k_scan1(const int* __restrict__ deg,
    int* __restrict__ inc, int* __restrict__ bsum, int N) {
  __shared__ int sm[SCAN_B];
  int g = blockIdx.x * SCAN_B + threadIdx.x;
  sm[threadIdx.x] = (g < N) ? deg[g] : 0;
  __syncthreads();
  for (int o = 1; o < SCAN_B; o <<= 1) {
    int t = (threadIdx.x >= o) ? sm[threadIdx.x - o] : 0;
    __syncthreads();
    sm[threadIdx.x] += t;
    __syncthreads();
  }
  if (g < N) inc[g] = sm[threadIdx.x];
  if (threadIdx.x == SCAN_B - 1) bsum[blockIdx.x] = sm[threadIdx.x];
}

__global__ __launch_bounds__(SCAN_B) void k_scan2(int* __restrict__ bsum, int nb) {
  __shared__ int sm[SCAN_B];
  __shared__ int carry;
  if (threadIdx.x == 0) carry = 0;
  __syncthreads();
  for (int base = 0; base < nb; base += SCAN_B) {
    int i = base + threadIdx.x;
    sm[threadIdx.x] = (i < nb) ? bsum[i] : 0;
    __syncthreads();
    if (threadIdx.x == 0) {
      int run = carry;
      int lim = nb - base < SCAN_B ? nb - base : SCAN_B;
      for (int j = 0; j < lim; ++j) { run += sm[j]; sm[j] = run; }
      carry = run;
    }
    __syncthreads();
    if (i < nb) bsum[i] = sm[threadIdx.x];
    __syncthreads();
  }
}

__global__ __launch_bounds__(SCAN_B) void k_scan3(const int* __restrict__ inc,
    const int* __restrict__ bsum, const int* __restrict__ deg,
    int* __restrict__ row, int* __restrict__ cursor, int N) {
  int g = blockIdx.x * SCAN_B + threadIdx.x;
  if (g >= N) return;
  int off = (blockIdx.x > 0) ? bsum[blockIdx.x - 1] : 0;
  int end = inc[g] + off;
  int st = end - deg[g];
  row[g] = st;
  cursor[g] = st;
  if (g == N - 1) row[N] = end;
}

__global__ __launch_bounds__(256) void k_scatter(const int* __restrict__ ei,
    int* __restrict__ cursor, int* __restrict__ ssrc, int* __restrict__ epos, int E) {
  int i = blockIdx.x * 256 + threadIdx.x;
  if (i >= E) return;
  int d = ei[E + i];
  int pos = atomicAdd(&cursor[d], 1);
  ssrc[pos] = ei[i];
  epos[i] = pos;
}

// ---- per-layer ----
// hw = h @ Wmsg ; esrc = hw . a_src ; edst = hw . a_dst   (wave per node)
__global__ __launch_bounds__(256) void k_node(const float* __restrict__ h,
    const float* __restrict__ Wmsg, const float* __restrict__ att,
    float* __restrict__ hw, float* __restrict__ esrc, float* __restrict__ edst,
    int N) {
  __shared__ float Ws[H * H];   // 16 KB
  __shared__ float hs[4][H];    // 1 KB
  for (int i = threadIdx.x; i < H * H; i += 256) Ws[i] = Wmsg[i];
  int nodeBase = blockIdx.x * 4;
  int wid = threadIdx.x >> 6, lane = threadIdx.x & 63;
  for (int i = threadIdx.x; i < 4 * H; i += 256) {
    int nn = nodeBase + (i >> 6);
    hs[i >> 6][i & 63] = (nn < N) ? h[(size_t)nn * H + (i & 63)] : 0.f;
  }
  __syncthreads();
  int n = nodeBase + wid;
  if (n >= N) return;
  float acc = 0.f;
  #pragma unroll 8
  for (int k = 0; k < H; ++k)
    acc = fmaf(hs[wid][k], Ws[k * H + lane], acc);
  hw[(size_t)n * H + lane] = acc;
  float vd = acc * att[lane];        // a_dst
  float vs = acc * att[H + lane];    // a_src
  #pragma unroll
  for (int o = 32; o >= 1; o >>= 1) {
    vd += __shfl_xor(vd, o);
    vs += __shfl_xor(vs, o);
  }
  if (lane == 0) { edst[n] = vd; esrc[n] = vs; }
}

// erel[r] = (rel_emb[r] @ W_relproj) . a_rel   — 1 block, 512 thr (wave per rel)
__global__ void k_rel(const float* __restrict__ rel_emb,
    const float* __restrict__ Wrp, const float* __restrict__ att,
    float* __restrict__ erel) {
  int r = threadIdx.x >> 6, lane = threadIdx.x & 63;
  float acc = 0.f;
  #pragma unroll
  for (int k = 0; k < 16; ++k)
    acc = fmaf(rel_emb[r * 16 + k], Wrp[k * H + lane], acc);
  float v = acc * att[2 * H + lane];
  #pragma unroll
  for (int o = 32; o >= 1; o >>= 1) v += __shfl_xor(v, o);
  if (lane == 0) erel[r] = v;
}

// per-edge logit, scattered into CSR position (no atomics)
__global__ __launch_bounds__(256) void k_edge1(const int* __restrict__ ei,
    const int* __restrict__ et, const float* __restrict__ ea,
    const float* __restrict__ esrc, const float* __restrict__ edst,
    const float* __restrict__ erel, const int* __restrict__ epos,
    float* __restrict__ ebuf, int E) {
  __shared__ float er[NRELS];
  if (threadIdx.x < NRELS) er[threadIdx.x] = erel[threadIdx.x];
  __syncthreads();
  int i = blockIdx.x * 256 + threadIdx.x;
  if (i >= E) return;
  int s = ei[i], d = ei[E + i];
  int t = et[i]; t = t < 0 ? 0 : (t > NRELS - 1 ? NRELS - 1 : t);
  float e = edst[d] + esrc[s] + er[t];
  e = e > 0.f ? e : 0.2f * e;                  // leaky_relu 0.2
  e += 0.1f * logf(fmaxf(ea[i], 1e-6f));      // conf term
  ebuf[epos[i]] = e;
}

// pull-style aggregation + finalize, wave per node, no atomics
__global__ __launch_bounds__(256) void k_agg(const int* __restrict__ row,
    const int* __restrict__ ssrc, const float* __restrict__ ebuf,
    const float* __restrict__ hw, const float* __restrict__ h,
    const float* __restrict__ bias, const float* __restrict__ ln_g,
    const float* __restrict__ ln_b, float* __restrict__ hout, int N) {
  int w = (blockIdx.x * 256 + threadIdx.x) >> 6;
  int lane = threadIdx.x & 63;
  if (w >= N) return;
  int st = row[w], en = row[w + 1];
  // segment max (exact)
  float m = -3.4e38f;
  for (int j = st + lane; j < en; j += 64) m = fmaxf(m, ebuf[j]);
  #pragma unroll
  for (int o = 32; o >= 1; o >>= 1) m = fmaxf(m, __shfl_xor(m, o));
  // weighted accumulation: feature-parallel, coalesced 256B hw line per edge
  float acc = 0.f, s = 0.f;
  #pragma unroll 2
  for (int j = st; j < en; ++j) {
    float ex = __expf(ebuf[j] - m);   // wave-uniform broadcast load
    int sj = ssrc[j];                 // wave-uniform broadcast load
    s += ex;
    acc = fmaf(hw[(size_t)sj * H + lane], ex, acc);
  }
  float o = (en > st) ? acc / s : 0.f;
  o += bias[lane];
  float v = h[(size_t)w * H + lane] + fmaxf(o, 0.f);
  float mu = v;
  #pragma unroll
  for (int off = 32; off >= 1; off >>= 1) mu += __shfl_xor(mu, off);
  mu *= (1.f / 64.f);
  float dv = v - mu;
  float var = dv * dv;
  #pragma unroll
  for (int off = 32; off >= 1; off >>= 1) var += __shfl_xor(var, off);
  var *= (1.f / 64.f);
  hout[(size_t)w * H + lane] = dv * rsqrtf(var + 1e-5f) * ln_g[lane] + ln_b[lane];
}

extern "C" void kernel_launch(void* const* d_in, const int* in_sizes, int n_in,
                              void* d_out, int out_size, void* d_ws, size_t ws_size,
                              hipStream_t stream) {
  const float* x       = (const float*)d_in[0];
  const float* W_in    = (const float*)d_in[1];
  const float* b_in    = (const float*)d_in[2];
  const float* W_msg   = (const float*)d_in[3];
  const float* rel_emb = (const float*)d_in[4];
  const float* W_rp    = (const float*)d_in[5];
  const float* att     = (const float*)d_in[6];
  const float* bias    = (const float*)d_in[7];
  const float* ln_g    = (const float*)d_in[8];
  const float* ln_b    = (const float*)d_in[9];
  const float* ea      = (const float*)d_in[10];
  const int*   ei      = (const int*)d_in[11];
  const int*   et      = (const int*)d_in[12];

  int N = in_sizes[0] / IN_DIM;
  int E = in_sizes[12];
  int L = in_sizes[7] / H;
  int R = in_sizes[5] / (L * H);   // 16
  int nb = (N + SCAN_B - 1) / SCAN_B;

  float* ws   = (float*)d_ws;
  float* h    = ws;                         // N*H
  float* hw   = h    + (size_t)N * H;       // N*H
  float* ebuf = hw   + (size_t)N * H;       // E
  float* esrc = ebuf + E;                   // N
  float* edst = esrc + N;                   // N
  float* erel = edst + N;                   // NRELS
  int* ssrc   = (int*)(erel + NRELS);       // E
  int* epos   = ssrc + E;                   // E
  int* row    = epos + E;                   // N+1
  int* cursor = row + N + 1;                // N
  int* deg    = cursor + N;                 // N
  int* inc    = deg + N;                    // N
  int* bsum   = inc + N;                    // nb

  int nb4 = (N + 3) / 4;
  k_input<<<nb4, 256, 0, stream>>>(x, W_in, b_in, h, N);

  // CSR build (amortized across layers)
  hipMemsetAsync(deg, 0, (size_t)N * sizeof(int), stream);
  k_hist<<<(E + 255) / 256, 256, 0, stream>>>(ei, deg, E);
  k_scan1<<<nb, SCAN_B, 0, stream>>>(deg, inc, bsum, N);
  k_scan2<<<1, SCAN_B, 0, stream>>>(bsum, nb);
  k_scan3<<<nb, SCAN_B, 0, stream>>>(inc, bsum, deg, row, cursor, N);
  k_scatter<<<(E + 255) / 256, 256, 0, stream>>>(ei, cursor, ssrc, epos, E);

  for (int l = 0; l < L; ++l) {
    k_node<<<nb4, 256, 0, stream>>>(h, W_msg + (size_t)l * H * H,
                                    att + (size_t)l * 3 * H, hw, esrc, edst, N);
    k_rel<<<1, 512, 0, stream>>>(rel_emb + (size_t)l * NRELS * R,
                                 W_rp + (size_t)l * R * H,
                                 att + (size_t)l * 3 * H, erel);
    k_edge1<<<(E + 255) / 256, 256, 0, stream>>>(ei, et, ea, esrc, edst, erel,
                                                 epos, ebuf, E);
    float* hout = (l == L - 1) ? (float*)d_out : h;
    k_agg<<<(N + 3) / 4, 256, 0, stream>>>(row, ssrc, ebuf, hw, h,
                                           bias + (size_t)l * H,
                                           ln_g + (size_t)l * H,
                                           ln_b + (size_t)l * H, hout, N);
  }
}

// Round 4
// 808.489 us; speedup vs baseline: 1.7696x; 1.0513x over previous
//
#include <hip/hip_runtime.h>
#include <math.h>

#define H 64
#define IN_DIM 128
#define NRELS 8
#define SCAN_B 512

// ---- h0 = relu(x @ W_in + b_in). 16 nodes/block, 4 nodes/wave ----
__global__ __launch_bounds__(256) void k_input(const float* __restrict__ x,
    const float* __restrict__ W_in, const float* __restrict__ b_in,
    float* __restrict__ h, int N) {
  __shared__ float Ws[IN_DIM * H];   // 32 KB
  __shared__ float xs[16 * IN_DIM];  // 8 KB
  for (int i = threadIdx.x; i < IN_DIM * H; i += 256) Ws[i] = W_in[i];
  int base = blockIdx.x * 16;
  for (int i = threadIdx.x; i < 16 * IN_DIM; i += 256) {
    int nn = base + (i >> 7);
    xs[i] = (nn < N) ? x[(size_t)nn * IN_DIM + (i & 127)] : 0.f;
  }
  __syncthreads();
  int wid = threadIdx.x >> 6, lane = threadIdx.x & 63;
  int n0 = base + wid * 4;
  float a0 = 0.f, a1 = 0.f, a2 = 0.f, a3 = 0.f;
  const float* xr = xs + wid * 4 * IN_DIM;
  #pragma unroll 4
  for (int k = 0; k < IN_DIM; ++k) {
    float wv = Ws[k * H + lane];
    a0 = fmaf(xr[k], wv, a0);
    a1 = fmaf(xr[IN_DIM + k], wv, a1);
    a2 = fmaf(xr[2 * IN_DIM + k], wv, a2);
    a3 = fmaf(xr[3 * IN_DIM + k], wv, a3);
  }
  float bb = b_in[lane];
  if (n0 + 0 < N) h[(size_t)(n0 + 0) * H + lane] = fmaxf(a0 + bb, 0.f);
  if (n0 + 1 < N) h[(size_t)(n0 + 1) * H + lane] = fmaxf(a1 + bb, 0.f);
  if (n0 + 2 < N) h[(size_t)(n0 + 2) * H + lane] = fmaxf(a2 + bb, 0.f);
  if (n0 + 3 < N) h[(size_t)(n0 + 3) * H + lane] = fmaxf(a3 + bb, 0.f);
}

// ---- CSR build (once per call) ----
__global__ __launch_bounds__(256) void k_hist(const int* __restrict__ ei,
    int* __restrict__ deg, int E) {
  int i = blockIdx.x * 256 + threadIdx.x;
  if (i < E) atomicAdd(&deg[ei[E + i]], 1);
}

__global__ __launch_bounds__(SCAN_B) void k_scan1(const int* __restrict__ deg,
    int* __restrict__ inc, int* __restrict__ bsum, int N) {
  __shared__ int sm[SCAN_B];
  int g = blockIdx.x * SCAN_B + threadIdx.x;
  sm[threadIdx.x] = (g < N) ? deg[g] : 0;
  __syncthreads();
  for (int o = 1; o < SCAN_B; o <<= 1) {
    int t = (threadIdx.x >= o) ? sm[threadIdx.x - o] : 0;
    __syncthreads();
    sm[threadIdx.x] += t;
    __syncthreads();
  }
  if (g < N) inc[g] = sm[threadIdx.x];
  if (threadIdx.x == SCAN_B - 1) bsum[blockIdx.x] = sm[threadIdx.x];
}

__global__ __launch_bounds__(SCAN_B) void k_scan2(int* __restrict__ bsum, int nb) {
  __shared__ int sm[SCAN_B];
  __shared__ int carry;
  if (threadIdx.x == 0) carry = 0;
  __syncthreads();
  for (int base = 0; base < nb; base += SCAN_B) {
    int i = base + threadIdx.x;
    sm[threadIdx.x] = (i < nb) ? bsum[i] : 0;
    __syncthreads();
    if (threadIdx.x == 0) {
      int run = carry;
      int lim = nb - base < SCAN_B ? nb - base : SCAN_B;
      for (int j = 0; j < lim; ++j) { run += sm[j]; sm[j] = run; }
      carry = run;
    }
    __syncthreads();
    if (i < nb) bsum[i] = sm[threadIdx.x];
    __syncthreads();
  }
}

__global__ __launch_bounds__(SCAN_B) void k_scan3(const int* __restrict__ inc,
    const int* __restrict__ bsum, const int* __restrict__ deg,
    int* __restrict__ row, int* __restrict__ cursor, int N) {
  int g = blockIdx.x * SCAN_B + threadIdx.x;
  if (g >= N) return;
  int off = (blockIdx.x > 0) ? bsum[blockIdx.x - 1] : 0;
  int end = inc[g] + off;
  int st = end - deg[g];
  row[g] = st;
  cursor[g] = st;
  if (g == N - 1) row[N] = end;
}

// scatter per-edge static record: {src | type<<20, 0.1*log(max(conf,1e-6))}
__global__ __launch_bounds__(256) void k_scatter(const int* __restrict__ ei,
    const int* __restrict__ et, const float* __restrict__ ea,
    int* __restrict__ cursor, int2* __restrict__ erec, int E) {
  int i = blockIdx.x * 256 + threadIdx.x;
  if (i >= E) return;
  int d = ei[E + i];
  int s = ei[i];
  int t = et[i]; t = t < 0 ? 0 : (t > NRELS - 1 ? NRELS - 1 : t);
  float cl = 0.1f * logf(fmaxf(ea[i], 1e-6f));
  int pos = atomicAdd(&cursor[d], 1);
  erec[pos] = make_int2(s | (t << 20), __float_as_int(cl));
}

// ---- per-layer ----
// hw = h @ Wmsg ; esrc/edst per node.  16 nodes/block, 4 nodes/wave.
__global__ __launch_bounds__(256) void k_node(const float* __restrict__ h,
    const float* __restrict__ Wmsg, const float* __restrict__ att,
    float* __restrict__ hw, float* __restrict__ esrc, float* __restrict__ edst,
    int N) {
  __shared__ float Ws[H * H];   // 16 KB
  __shared__ float hs[16 * H];  // 4 KB
  for (int i = threadIdx.x; i < H * H; i += 256) Ws[i] = Wmsg[i];
  int base = blockIdx.x * 16;
  for (int i = threadIdx.x; i < 16 * H; i += 256) {
    int nn = base + (i >> 6);
    hs[i] = (nn < N) ? h[(size_t)nn * H + (i & 63)] : 0.f;
  }
  __syncthreads();
  int wid = threadIdx.x >> 6, lane = threadIdx.x & 63;
  int n0 = base + wid * 4;
  float a0 = 0.f, a1 = 0.f, a2 = 0.f, a3 = 0.f;
  const float* hr = hs + wid * 4 * H;
  #pragma unroll 4
  for (int k = 0; k < H; ++k) {
    float wv = Ws[k * H + lane];
    a0 = fmaf(hr[k], wv, a0);
    a1 = fmaf(hr[H + k], wv, a1);
    a2 = fmaf(hr[2 * H + k], wv, a2);
    a3 = fmaf(hr[3 * H + k], wv, a3);
  }
  float ad = att[lane], as = att[H + lane];
  float acc[4] = {a0, a1, a2, a3};
  #pragma unroll
  for (int i = 0; i < 4; ++i) {
    int n = n0 + i;
    if (n >= N) break;
    hw[(size_t)n * H + lane] = acc[i];
    float vd = acc[i] * ad, vs = acc[i] * as;
    #pragma unroll
    for (int o = 32; o >= 1; o >>= 1) {
      vd += __shfl_xor(vd, o);
      vs += __shfl_xor(vs, o);
    }
    if (lane == 0) { edst[n] = vd; esrc[n] = vs; }
  }
}

// erel[l][r] = (rel_emb[l,r] @ W_relproj[l]) . a_rel[l] — grid L, wave per rel
__global__ void k_rel(const float* __restrict__ rel_emb,
    const float* __restrict__ Wrp, const float* __restrict__ att,
    float* __restrict__ erel, int R) {
  int l = blockIdx.x;
  int r = threadIdx.x >> 6, lane = threadIdx.x & 63;
  const float* re = rel_emb + ((size_t)l * NRELS + r) * R;
  const float* wp = Wrp + (size_t)l * R * H;
  float acc = 0.f;
  for (int k = 0; k < R; ++k) acc = fmaf(re[k], wp[k * H + lane], acc);
  float v = acc * att[(size_t)l * 3 * H + 2 * H + lane];
  #pragma unroll
  for (int o = 32; o >= 1; o >>= 1) v += __shfl_xor(v, o);
  if (lane == 0) erel[l * NRELS + r] = v;
}

// pull aggregation + finalize, wave per node; logits recomputed from erec
__global__ __launch_bounds__(256) void k_agg(const int* __restrict__ row,
    const int2* __restrict__ erec, const float* __restrict__ esrc,
    const float* __restrict__ edst, const float* __restrict__ erel,
    const float* __restrict__ hw, const float* __restrict__ h,
    const float* __restrict__ bias, const float* __restrict__ ln_g,
    const float* __restrict__ ln_b, float* __restrict__ hout, int N) {
  __shared__ float er[NRELS];
  if (threadIdx.x < NRELS) er[threadIdx.x] = erel[threadIdx.x];
  __syncthreads();
  int w = (blockIdx.x * 256 + threadIdx.x) >> 6;
  int lane = threadIdx.x & 63;
  if (w >= N) return;
  int st = row[w], en = row[w + 1];
  float ed = edst[w];
  // pass 1: exact segment max (lane-parallel over edges)
  float m = -3.4e38f;
  for (int j = st + lane; j < en; j += 64) {
    int2 r = erec[j];
    float e = ed + esrc[r.x & 0xFFFFF] + er[(r.x >> 20) & 7];
    e = e > 0.f ? e : 0.2f * e;
    m = fmaxf(m, e + __int_as_float(r.y));
  }
  #pragma unroll
  for (int o = 32; o >= 1; o >>= 1) m = fmaxf(m, __shfl_xor(m, o));
  // pass 2: feature-parallel weighted accumulation
  float acc = 0.f, ssum = 0.f;
  for (int j = st; j < en; ++j) {
    int2 r = erec[j];
    int sj = r.x & 0xFFFFF;
    float e = ed + esrc[sj] + er[(r.x >> 20) & 7];
    e = e > 0.f ? e : 0.2f * e;
    e += __int_as_float(r.y);
    float p = __expf(e - m);
    ssum += p;
    acc = fmaf(hw[(size_t)sj * H + lane], p, acc);
  }
  float o = (en > st) ? acc / ssum : 0.f;
  o += bias[lane];
  float v = h[(size_t)w * H + lane] + fmaxf(o, 0.f);
  float mu = v;
  #pragma unroll
  for (int off = 32; off >= 1; off >>= 1) mu += __shfl_xor(mu, off);
  mu *= (1.f / 64.f);
  float dv = v - mu;
  float var = dv * dv;
  #pragma unroll
  for (int off = 32; off >= 1; off >>= 1) var += __shfl_xor(var, off);
  var *= (1.f / 64.f);
  hout[(size_t)w * H + lane] = dv * rsqrtf(var + 1e-5f) * ln_g[lane] + ln_b[lane];
}

extern "C" void kernel_launch(void* const* d_in, const int* in_sizes, int n_in,
                              void* d_out, int out_size, void* d_ws, size_t ws_size,
                              hipStream_t stream) {
  const float* x       = (const float*)d_in[0];
  const float* W_in    = (const float*)d_in[1];
  const float* b_in    = (const float*)d_in[2];
  const float* W_msg   = (const float*)d_in[3];
  const float* rel_emb = (const float*)d_in[4];
  const float* W_rp    = (const float*)d_in[5];
  const float* att     = (const float*)d_in[6];
  const float* bias    = (const float*)d_in[7];
  const float* ln_g    = (const float*)d_in[8];
  const float* ln_b    = (const float*)d_in[9];
  const float* ea      = (const float*)d_in[10];
  const int*   ei      = (const int*)d_in[11];
  const int*   et      = (const int*)d_in[12];

  int N = in_sizes[0] / IN_DIM;
  int E = in_sizes[12];
  int L = in_sizes[7] / H;
  int R = in_sizes[5] / (L * H);   // 16
  int nb = (N + SCAN_B - 1) / SCAN_B;

  float* ws   = (float*)d_ws;
  float* h    = ws;                         // N*H
  float* hw   = h    + (size_t)N * H;       // N*H
  int2*  erec = (int2*)(hw + (size_t)N * H); // E (8B-aligned: 2*N*H floats even)
  float* esrc = (float*)(erec + E);         // N
  float* edst = esrc + N;                   // N
  float* erel = edst + N;                   // L*NRELS
  int* row    = (int*)(erel + L * NRELS);   // N+1
  int* cursor = row + N + 1;                // N
  int* deg    = cursor + N;                 // N
  int* inc    = deg + N;                    // N
  int* bsum   = inc + N;                    // nb

  int nb16 = (N + 15) / 16;
  k_input<<<nb16, 256, 0, stream>>>(x, W_in, b_in, h, N);

  // CSR build (amortized across layers)
  hipMemsetAsync(deg, 0, (size_t)N * sizeof(int), stream);
  k_hist<<<(E + 255) / 256, 256, 0, stream>>>(ei, deg, E);
  k_scan1<<<nb, SCAN_B, 0, stream>>>(deg, inc, bsum, N);
  k_scan2<<<1, SCAN_B, 0, stream>>>(bsum, nb);
  k_scan3<<<nb, SCAN_B, 0, stream>>>(inc, bsum, deg, row, cursor, N);
  k_scatter<<<(E + 255) / 256, 256, 0, stream>>>(ei, et, ea, cursor, erec, E);
  k_rel<<<L, 512, 0, stream>>>(rel_emb, W_rp, att, erel, R);

  for (int l = 0; l < L; ++l) {
    k_node<<<nb16, 256, 0, stream>>>(h, W_msg + (size_t)l * H * H,
                                     att + (size_t)l * 3 * H, hw, esrc, edst, N);
    float* hout = (l == L - 1) ? (float*)d_out : h;
    k_agg<<<(N + 3) / 4, 256, 0, stream>>>(row, erec, esrc, edst,
                                           erel + (size_t)l * NRELS, hw, h,
                                           bias + (size_t)l * H,
                                           ln_g + (size_t)l * H,
                                           ln_b + (size_t)l * H, hout, N);
  }
}

// Round 5
// 588.576 us; speedup vs baseline: 2.4308x; 1.3736x over previous
//
#include <hip/hip_runtime.h>
#include <math.h>

#define H 64
#define IN_DIM 128
#define NRELS 8
#define SCAN_B 512
#define DEGCAP 128

// ---- h0 = relu(x @ W_in + b_in). 16 nodes/block, 4 nodes/wave ----
__global__ __launch_bounds__(256) void k_input(const float* __restrict__ x,
    const float* __restrict__ W_in, const float* __restrict__ b_in,
    float* __restrict__ h, int N) {
  __shared__ float Ws[IN_DIM * H];   // 32 KB
  __shared__ float xs[16 * IN_DIM];  // 8 KB
  for (int i = threadIdx.x; i < IN_DIM * H; i += 256) Ws[i] = W_in[i];
  int base = blockIdx.x * 16;
  for (int i = threadIdx.x; i < 16 * IN_DIM; i += 256) {
    int nn = base + (i >> 7);
    xs[i] = (nn < N) ? x[(size_t)nn * IN_DIM + (i & 127)] : 0.f;
  }
  __syncthreads();
  int wid = threadIdx.x >> 6, lane = threadIdx.x & 63;
  int n0 = base + wid * 4;
  float a0 = 0.f, a1 = 0.f, a2 = 0.f, a3 = 0.f;
  const float* xr = xs + wid * 4 * IN_DIM;
  #pragma unroll 4
  for (int k = 0; k < IN_DIM; ++k) {
    float wv = Ws[k * H + lane];
    a0 = fmaf(xr[k], wv, a0);
    a1 = fmaf(xr[IN_DIM + k], wv, a1);
    a2 = fmaf(xr[2 * IN_DIM + k], wv, a2);
    a3 = fmaf(xr[3 * IN_DIM + k], wv, a3);
  }
  float bb = b_in[lane];
  if (n0 + 0 < N) h[(size_t)(n0 + 0) * H + lane] = fmaxf(a0 + bb, 0.f);
  if (n0 + 1 < N) h[(size_t)(n0 + 1) * H + lane] = fmaxf(a1 + bb, 0.f);
  if (n0 + 2 < N) h[(size_t)(n0 + 2) * H + lane] = fmaxf(a2 + bb, 0.f);
  if (n0 + 3 < N) h[(size_t)(n0 + 3) * H + lane] = fmaxf(a3 + bb, 0.f);
}

// ---- CSR build (once per call) ----
__global__ __launch_bounds__(256) void k_hist(const int* __restrict__ ei,
    int* __restrict__ deg, int E) {
  int i = blockIdx.x * 256 + threadIdx.x;
  if (i < E) atomicAdd(&deg[ei[E + i]], 1);
}

__global__ __launch_bounds__(SCAN_B) void k_scan1(const int* __restrict__ deg,
    int* __restrict__ inc, int* __restrict__ bsum, int N) {
  __shared__ int sm[SCAN_B];
  int g = blockIdx.x * SCAN_B + threadIdx.x;
  sm[threadIdx.x] = (g < N) ? deg[g] : 0;
  __syncthreads();
  for (int o = 1; o < SCAN_B; o <<= 1) {
    int t = (threadIdx.x >= o) ? sm[threadIdx.x - o] : 0;
    __syncthreads();
    sm[threadIdx.x] += t;
    __syncthreads();
  }
  if (g < N) inc[g] = sm[threadIdx.x];
  if (threadIdx.x == SCAN_B - 1) bsum[blockIdx.x] = sm[threadIdx.x];
}

__global__ __launch_bounds__(SCAN_B) void k_scan2(int* __restrict__ bsum, int nb) {
  __shared__ int sm[SCAN_B];
  __shared__ int carry;
  if (threadIdx.x == 0) carry = 0;
  __syncthreads();
  for (int base = 0; base < nb; base += SCAN_B) {
    int i = base + threadIdx.x;
    sm[threadIdx.x] = (i < nb) ? bsum[i] : 0;
    __syncthreads();
    if (threadIdx.x == 0) {
      int run = carry;
      int lim = nb - base < SCAN_B ? nb - base : SCAN_B;
      for (int j = 0; j < lim; ++j) { run += sm[j]; sm[j] = run; }
      carry = run;
    }
    __syncthreads();
    if (i < nb) bsum[i] = sm[threadIdx.x];
    __syncthreads();
  }
}

__global__ __launch_bounds__(SCAN_B) void k_scan3(const int* __restrict__ inc,
    const int* __restrict__ bsum, const int* __restrict__ deg,
    int* __restrict__ row, int* __restrict__ cursor, int N) {
  int g = blockIdx.x * SCAN_B + threadIdx.x;
  if (g >= N) return;
  int off = (blockIdx.x > 0) ? bsum[blockIdx.x - 1] : 0;
  int end = inc[g] + off;
  int st = end - deg[g];
  row[g] = st;
  cursor[g] = st;
  if (g == N - 1) row[N] = end;
}

// scatter per-edge static record: {src | type<<20, 0.1*log(max(conf,1e-6))}
__global__ __launch_bounds__(256) void k_scatter(const int* __restrict__ ei,
    const int* __restrict__ et, const float* __restrict__ ea,
    int* __restrict__ cursor, int2* __restrict__ erec, int E) {
  int i = blockIdx.x * 256 + threadIdx.x;
  if (i >= E) return;
  int d = ei[E + i];
  int s = ei[i];
  int t = et[i]; t = t < 0 ? 0 : (t > NRELS - 1 ? NRELS - 1 : t);
  float cl = 0.1f * logf(fmaxf(ea[i], 1e-6f));
  int pos = atomicAdd(&cursor[d], 1);
  erec[pos] = make_int2(s | (t << 20), __float_as_int(cl));
}

// ---- per-layer ----
// hw = h @ Wmsg ; esrc/edst per node.  16 nodes/block, 4 nodes/wave.
__global__ __launch_bounds__(256) void k_node(const float* __restrict__ h,
    const float* __restrict__ Wmsg, const float* __restrict__ att,
    float* __restrict__ hw, float* __restrict__ esrc, float* __restrict__ edst,
    int N) {
  __shared__ float Ws[H * H];   // 16 KB
  __shared__ float hs[16 * H];  // 4 KB
  for (int i = threadIdx.x; i < H * H; i += 256) Ws[i] = Wmsg[i];
  int base = blockIdx.x * 16;
  for (int i = threadIdx.x; i < 16 * H; i += 256) {
    int nn = base + (i >> 6);
    hs[i] = (nn < N) ? h[(size_t)nn * H + (i & 63)] : 0.f;
  }
  __syncthreads();
  int wid = threadIdx.x >> 6, lane = threadIdx.x & 63;
  int n0 = base + wid * 4;
  float a0 = 0.f, a1 = 0.f, a2 = 0.f, a3 = 0.f;
  const float* hr = hs + wid * 4 * H;
  #pragma unroll 4
  for (int k = 0; k < H; ++k) {
    float wv = Ws[k * H + lane];
    a0 = fmaf(hr[k], wv, a0);
    a1 = fmaf(hr[H + k], wv, a1);
    a2 = fmaf(hr[2 * H + k], wv, a2);
    a3 = fmaf(hr[3 * H + k], wv, a3);
  }
  float ad = att[lane], as = att[H + lane];
  float acc[4] = {a0, a1, a2, a3};
  #pragma unroll
  for (int i = 0; i < 4; ++i) {
    int n = n0 + i;
    if (n >= N) break;
    hw[(size_t)n * H + lane] = acc[i];
    float vd = acc[i] * ad, vs = acc[i] * as;
    #pragma unroll
    for (int o = 32; o >= 1; o >>= 1) {
      vd += __shfl_xor(vd, o);
      vs += __shfl_xor(vs, o);
    }
    if (lane == 0) { edst[n] = vd; esrc[n] = vs; }
  }
}

// erel[l][r] = (rel_emb[l,r] @ W_relproj[l]) . a_rel[l] — grid L, wave per rel
__global__ void k_rel(const float* __restrict__ rel_emb,
    const float* __restrict__ Wrp, const float* __restrict__ att,
    float* __restrict__ erel, int R) {
  int l = blockIdx.x;
  int r = threadIdx.x >> 6, lane = threadIdx.x & 63;
  const float* re = rel_emb + ((size_t)l * NRELS + r) * R;
  const float* wp = Wrp + (size_t)l * R * H;
  float acc = 0.f;
  for (int k = 0; k < R; ++k) acc = fmaf(re[k], wp[k * H + lane], acc);
  float v = acc * att[(size_t)l * 3 * H + 2 * H + lane];
  #pragma unroll
  for (int o = 32; o >= 1; o >>= 1) v += __shfl_xor(v, o);
  if (lane == 0) erel[l * NRELS + r] = v;
}

// pull aggregation + finalize, wave per node.
// Pass 1 (lane-parallel): compute logits once, cache {e,src} in LDS, get max.
// Pass 2 (feature-parallel): 4-deep pipelined hw row gathers from LDS indices.
__global__ __launch_bounds__(256) void k_agg(const int* __restrict__ row,
    const int2* __restrict__ erec, const float* __restrict__ esrc,
    const float* __restrict__ edst, const float* __restrict__ erel,
    const float* __restrict__ hw, const float* __restrict__ h,
    const float* __restrict__ bias, const float* __restrict__ ln_g,
    const float* __restrict__ ln_b, float* __restrict__ hout, int N) {
  __shared__ float er[NRELS];
  __shared__ float els[4][DEGCAP];  // per-wave cached logits
  __shared__ int   sls[4][DEGCAP];  // per-wave cached src indices
  if (threadIdx.x < NRELS) er[threadIdx.x] = erel[threadIdx.x];
  __syncthreads();
  int wid = threadIdx.x >> 6, lane = threadIdx.x & 63;
  int w = blockIdx.x * 4 + wid;
  if (w >= N) return;
  int st = row[w], en = row[w + 1];
  int deg = en - st;
  float ed = edst[w];
  float m = -3.4e38f;
  float acc = 0.f, ssum = 0.f;

  if (deg <= DEGCAP) {
    // pass 1: lane-parallel logit compute + LDS cache + max
    for (int j = st + lane; j < en; j += 64) {
      int2 r = erec[j];
      int sj = r.x & 0xFFFFF;
      float e = ed + esrc[sj] + er[(r.x >> 20) & 7];
      e = e > 0.f ? e : 0.2f * e;
      e += __int_as_float(r.y);
      els[wid][j - st] = e;
      sls[wid][j - st] = sj;
      m = fmaxf(m, e);
    }
    #pragma unroll
    for (int o = 32; o >= 1; o >>= 1) m = fmaxf(m, __shfl_xor(m, o));
    // pass 2: 4-wide pipelined gather (same serial accumulation order)
    int k = 0;
    for (; k + 4 <= deg; k += 4) {
      int s0 = sls[wid][k], s1 = sls[wid][k + 1];
      int s2 = sls[wid][k + 2], s3 = sls[wid][k + 3];
      float h0 = hw[(size_t)s0 * H + lane];
      float h1 = hw[(size_t)s1 * H + lane];
      float h2 = hw[(size_t)s2 * H + lane];
      float h3 = hw[(size_t)s3 * H + lane];
      float p0 = __expf(els[wid][k] - m);
      float p1 = __expf(els[wid][k + 1] - m);
      float p2 = __expf(els[wid][k + 2] - m);
      float p3 = __expf(els[wid][k + 3] - m);
      ssum += p0; acc = fmaf(h0, p0, acc);
      ssum += p1; acc = fmaf(h1, p1, acc);
      ssum += p2; acc = fmaf(h2, p2, acc);
      ssum += p3; acc = fmaf(h3, p3, acc);
    }
    for (; k < deg; ++k) {
      int sj = sls[wid][k];
      float hv = hw[(size_t)sj * H + lane];
      float p = __expf(els[wid][k] - m);
      ssum += p; acc = fmaf(hv, p, acc);
    }
  } else {
    // fallback: two-pass recompute (degree > DEGCAP; ~never for this graph)
    for (int j = st + lane; j < en; j += 64) {
      int2 r = erec[j];
      float e = ed + esrc[r.x & 0xFFFFF] + er[(r.x >> 20) & 7];
      e = e > 0.f ? e : 0.2f * e;
      m = fmaxf(m, e + __int_as_float(r.y));
    }
    #pragma unroll
    for (int o = 32; o >= 1; o >>= 1) m = fmaxf(m, __shfl_xor(m, o));
    for (int j = st; j < en; ++j) {
      int2 r = erec[j];
      int sj = r.x & 0xFFFFF;
      float e = ed + esrc[sj] + er[(r.x >> 20) & 7];
      e = e > 0.f ? e : 0.2f * e;
      e += __int_as_float(r.y);
      float p = __expf(e - m);
      ssum += p;
      acc = fmaf(hw[(size_t)sj * H + lane], p, acc);
    }
  }

  float o = (deg > 0) ? acc / ssum : 0.f;
  o += bias[lane];
  float v = h[(size_t)w * H + lane] + fmaxf(o, 0.f);
  float mu = v;
  #pragma unroll
  for (int off = 32; off >= 1; off >>= 1) mu += __shfl_xor(mu, off);
  mu *= (1.f / 64.f);
  float dv = v - mu;
  float var = dv * dv;
  #pragma unroll
  for (int off = 32; off >= 1; off >>= 1) var += __shfl_xor(var, off);
  var *= (1.f / 64.f);
  hout[(size_t)w * H + lane] = dv * rsqrtf(var + 1e-5f) * ln_g[lane] + ln_b[lane];
}

extern "C" void kernel_launch(void* const* d_in, const int* in_sizes, int n_in,
                              void* d_out, int out_size, void* d_ws, size_t ws_size,
                              hipStream_t stream) {
  const float* x       = (const float*)d_in[0];
  const float* W_in    = (const float*)d_in[1];
  const float* b_in    = (const float*)d_in[2];
  const float* W_msg   = (const float*)d_in[3];
  const float* rel_emb = (const float*)d_in[4];
  const float* W_rp    = (const float*)d_in[5];
  const float* att     = (const float*)d_in[6];
  const float* bias    = (const float*)d_in[7];
  const float* ln_g    = (const float*)d_in[8];
  const float* ln_b    = (const float*)d_in[9];
  const float* ea      = (const float*)d_in[10];
  const int*   ei      = (const int*)d_in[11];
  const int*   et      = (const int*)d_in[12];

  int N = in_sizes[0] / IN_DIM;
  int E = in_sizes[12];
  int L = in_sizes[7] / H;
  int R = in_sizes[5] / (L * H);   // 16
  int nb = (N + SCAN_B - 1) / SCAN_B;

  float* ws   = (float*)d_ws;
  float* h    = ws;                          // N*H
  float* hw   = h    + (size_t)N * H;        // N*H
  int2*  erec = (int2*)(hw + (size_t)N * H); // E (8B aligned: 2*N*H even)
  float* esrc = (float*)(erec + E);          // N
  float* edst = esrc + N;                    // N
  float* erel = edst + N;                    // L*NRELS
  int* row    = (int*)(erel + L * NRELS);    // N+1
  int* cursor = row + N + 1;                 // N
  int* deg    = cursor + N;                  // N
  int* inc    = deg + N;                     // N
  int* bsum   = inc + N;                     // nb

  int nb16 = (N + 15) / 16;
  k_input<<<nb16, 256, 0, stream>>>(x, W_in, b_in, h, N);

  // CSR build (amortized across layers)
  hipMemsetAsync(deg, 0, (size_t)N * sizeof(int), stream);
  k_hist<<<(E + 255) / 256, 256, 0, stream>>>(ei, deg, E);
  k_scan1<<<nb, SCAN_B, 0, stream>>>(deg, inc, bsum, N);
  k_scan2<<<1, SCAN_B, 0, stream>>>(bsum, nb);
  k_scan3<<<nb, SCAN_B, 0, stream>>>(inc, bsum, deg, row, cursor, N);
  k_scatter<<<(E + 255) / 256, 256, 0, stream>>>(ei, et, ea, cursor, erec, E);
  k_rel<<<L, 512, 0, stream>>>(rel_emb, W_rp, att, erel, R);

  for (int l = 0; l < L; ++l) {
    k_node<<<nb16, 256, 0, stream>>>(h, W_msg + (size_t)l * H * H,
                                     att + (size_t)l * 3 * H, hw, esrc, edst, N);
    float* hout = (l == L - 1) ? (float*)d_out : h;
    k_agg<<<(N + 3) / 4, 256, 0, stream>>>(row, erec, esrc, edst,
                                           erel + (size_t)l * NRELS, hw, h,
                                           bias + (size_t)l * H,
                                           ln_g + (size_t)l * H,
                                           ln_b + (size_t)l * H, hout, N);
  }
}

// Round 6
// 583.771 us; speedup vs baseline: 2.4508x; 1.0082x over previous
//
#include <hip/hip_runtime.h>
#include <math.h>

#define H 64
#define IN_DIM 128
#define NRELS 8
#define SCAN_B 512
#define DEGCAP 128
#define CHUNK 8192
#define MAXBUCK 512

// ---- h0 = relu(x @ W_in + b_in). 16 nodes/block, 4 nodes/wave ----
__global__ __launch_bounds__(256) void k_input(const float* __restrict__ x,
    const float* __restrict__ W_in, const float* __restrict__ b_in,
    float* __restrict__ h, int N) {
  __shared__ float Ws[IN_DIM * H];   // 32 KB
  __shared__ float xs[16 * IN_DIM];  // 8 KB
  for (int i = threadIdx.x; i < IN_DIM * H; i += 256) Ws[i] = W_in[i];
  int base = blockIdx.x * 16;
  for (int i = threadIdx.x; i < 16 * IN_DIM; i += 256) {
    int nn = base + (i >> 7);
    xs[i] = (nn < N) ? x[(size_t)nn * IN_DIM + (i & 127)] : 0.f;
  }
  __syncthreads();
  int wid = threadIdx.x >> 6, lane = threadIdx.x & 63;
  int n0 = base + wid * 4;
  float a0 = 0.f, a1 = 0.f, a2 = 0.f, a3 = 0.f;
  const float* xr = xs + wid * 4 * IN_DIM;
  #pragma unroll 4
  for (int k = 0; k < IN_DIM; ++k) {
    float wv = Ws[k * H + lane];
    a0 = fmaf(xr[k], wv, a0);
    a1 = fmaf(xr[IN_DIM + k], wv, a1);
    a2 = fmaf(xr[2 * IN_DIM + k], wv, a2);
    a3 = fmaf(xr[3 * IN_DIM + k], wv, a3);
  }
  float bb = b_in[lane];
  if (n0 + 0 < N) h[(size_t)(n0 + 0) * H + lane] = fmaxf(a0 + bb, 0.f);
  if (n0 + 1 < N) h[(size_t)(n0 + 1) * H + lane] = fmaxf(a1 + bb, 0.f);
  if (n0 + 2 < N) h[(size_t)(n0 + 2) * H + lane] = fmaxf(a2 + bb, 0.f);
  if (n0 + 3 < N) h[(size_t)(n0 + 3) * H + lane] = fmaxf(a3 + bb, 0.f);
}

// ---- CSR build ----
__global__ __launch_bounds__(256) void k_hist(const int* __restrict__ ei,
    int* __restrict__ deg, int E) {
  int i = blockIdx.x * 256 + threadIdx.x;
  if (i < E) atomicAdd(&deg[ei[E + i]], 1);
}

__global__ __launch_bounds__(SCAN_B) void k_scan1(const int* __restrict__ deg,
    int* __restrict__ inc, int* __restrict__ bsum, int N) {
  __shared__ int sm[SCAN_B];
  int g = blockIdx.x * SCAN_B + threadIdx.x;
  sm[threadIdx.x] = (g < N) ? deg[g] : 0;
  __syncthreads();
  for (int o = 1; o < SCAN_B; o <<= 1) {
    int t = (threadIdx.x >= o) ? sm[threadIdx.x - o] : 0;
    __syncthreads();
    sm[threadIdx.x] += t;
    __syncthreads();
  }
  if (g < N) inc[g] = sm[threadIdx.x];
  if (threadIdx.x == SCAN_B - 1) bsum[blockIdx.x] = sm[threadIdx.x];
}

__global__ __launch_bounds__(SCAN_B) void k_scan2(int* __restrict__ bsum, int nb) {
  __shared__ int sm[SCAN_B];
  __shared__ int carry;
  if (threadIdx.x == 0) carry = 0;
  __syncthreads();
  for (int base = 0; base < nb; base += SCAN_B) {
    int i = base + threadIdx.x;
    sm[threadIdx.x] = (i < nb) ? bsum[i] : 0;
    __syncthreads();
    if (threadIdx.x == 0) {
      int run = carry;
      int lim = nb - base < SCAN_B ? nb - base : SCAN_B;
      for (int j = 0; j < lim; ++j) { run += sm[j]; sm[j] = run; }
      carry = run;
    }
    __syncthreads();
    if (i < nb) bsum[i] = sm[threadIdx.x];
    __syncthreads();
  }
}

// row/cursor from inclusive node-degree scan
__global__ __launch_bounds__(SCAN_B) void k_scan3(const int* __restrict__ inc,
    const int* __restrict__ bsum, const int* __restrict__ deg,
    int* __restrict__ row, int* __restrict__ cursor, int N) {
  int g = blockIdx.x * SCAN_B + threadIdx.x;
  if (g >= N) return;
  int off = (blockIdx.x > 0) ? bsum[blockIdx.x - 1] : 0;
  int end = inc[g] + off;
  int st = end - deg[g];
  row[g] = st;
  cursor[g] = st;
  if (g == N - 1) row[N] = end;
}

// exclusive scan output for the (bin,wg) counts matrix
__global__ __launch_bounds__(SCAN_B) void k_scan3b(const int* __restrict__ inc,
    const int* __restrict__ bsum, const int* __restrict__ cnt,
    int* __restrict__ woff, int M) {
  int g = blockIdx.x * SCAN_B + threadIdx.x;
  if (g >= M) return;
  int off = (blockIdx.x > 0) ? bsum[blockIdx.x - 1] : 0;
  woff[g] = inc[g] + off - cnt[g];
}

// per-wg histogram of dst buckets: counts[bin*nwg + wg]
__global__ __launch_bounds__(256) void k_bhist(const int* __restrict__ ei,
    int* __restrict__ counts, int E, int nwg, int nbuck, int bshift) {
  __shared__ int cnt[MAXBUCK];
  for (int b = threadIdx.x; b < nbuck; b += 256) cnt[b] = 0;
  __syncthreads();
  int wg = blockIdx.x;
  int lo = wg * CHUNK, hi = lo + CHUNK < E ? lo + CHUNK : E;
  for (int j = lo + threadIdx.x; j < hi; j += 256)
    atomicAdd(&cnt[ei[E + j] >> bshift], 1);
  __syncthreads();
  for (int b = threadIdx.x; b < nbuck; b += 256)
    counts[(size_t)b * nwg + wg] = cnt[b];
}

// binned scatter: each wg appends into its private per-bin windows
__global__ __launch_bounds__(256) void k_binscat(const int* __restrict__ ei,
    const int* __restrict__ et, const float* __restrict__ ea,
    const int* __restrict__ woff, int4* __restrict__ staged,
    int E, int nwg, int nbuck, int bshift) {
  __shared__ int cur[MAXBUCK];
  int wg = blockIdx.x;
  for (int b = threadIdx.x; b < nbuck; b += 256)
    cur[b] = woff[(size_t)b * nwg + wg];
  __syncthreads();
  int lo = wg * CHUNK, hi = lo + CHUNK < E ? lo + CHUNK : E;
  for (int j = lo + threadIdx.x; j < hi; j += 256) {
    int s = ei[j], d = ei[E + j];
    int t = et[j]; t = t < 0 ? 0 : (t > NRELS - 1 ? NRELS - 1 : t);
    float cl = 0.1f * logf(fmaxf(ea[j], 1e-6f));
    int pos = atomicAdd(&cur[d >> bshift], 1);
    staged[pos] = make_int4(s | (t << 20), d, __float_as_int(cl), 0);
  }
}

// refine bucket -> exact CSR position (bucket window is L2-resident)
__global__ __launch_bounds__(256) void k_scat2(const int4* __restrict__ staged,
    const int* __restrict__ woff, int* __restrict__ cursor,
    int2* __restrict__ erec, int E, int nwg, int nbuck) {
  int b = blockIdx.x;
  int lo = woff[(size_t)b * nwg];
  int hi = (b + 1 < nbuck) ? woff[(size_t)(b + 1) * nwg] : E;
  for (int j = lo + threadIdx.x; j < hi; j += 256) {
    int4 r = staged[j];
    int pos = atomicAdd(&cursor[r.y], 1);
    erec[pos] = make_int2(r.x, r.z);
  }
}

// ---- per-layer ----
__global__ __launch_bounds__(256) void k_node(const float* __restrict__ h,
    const float* __restrict__ Wmsg, const float* __restrict__ att,
    float* __restrict__ hw, float* __restrict__ esrc, float* __restrict__ edst,
    int N) {
  __shared__ float Ws[H * H];   // 16 KB
  __shared__ float hs[16 * H];  // 4 KB
  for (int i = threadIdx.x; i < H * H; i += 256) Ws[i] = Wmsg[i];
  int base = blockIdx.x * 16;
  for (int i = threadIdx.x; i < 16 * H; i += 256) {
    int nn = base + (i >> 6);
    hs[i] = (nn < N) ? h[(size_t)nn * H + (i & 63)] : 0.f;
  }
  __syncthreads();
  int wid = threadIdx.x >> 6, lane = threadIdx.x & 63;
  int n0 = base + wid * 4;
  float a0 = 0.f, a1 = 0.f, a2 = 0.f, a3 = 0.f;
  const float* hr = hs + wid * 4 * H;
  #pragma unroll 4
  for (int k = 0; k < H; ++k) {
    float wv = Ws[k * H + lane];
    a0 = fmaf(hr[k], wv, a0);
    a1 = fmaf(hr[H + k], wv, a1);
    a2 = fmaf(hr[2 * H + k], wv, a2);
    a3 = fmaf(hr[3 * H + k], wv, a3);
  }
  float ad = att[lane], as = att[H + lane];
  float acc[4] = {a0, a1, a2, a3};
  #pragma unroll
  for (int i = 0; i < 4; ++i) {
    int n = n0 + i;
    if (n >= N) break;
    hw[(size_t)n * H + lane] = acc[i];
    float vd = acc[i] * ad, vs = acc[i] * as;
    #pragma unroll
    for (int o = 32; o >= 1; o >>= 1) {
      vd += __shfl_xor(vd, o);
      vs += __shfl_xor(vs, o);
    }
    if (lane == 0) { edst[n] = vd; esrc[n] = vs; }
  }
}

__global__ void k_rel(const float* __restrict__ rel_emb,
    const float* __restrict__ Wrp, const float* __restrict__ att,
    float* __restrict__ erel, int R) {
  int l = blockIdx.x;
  int r = threadIdx.x >> 6, lane = threadIdx.x & 63;
  const float* re = rel_emb + ((size_t)l * NRELS + r) * R;
  const float* wp = Wrp + (size_t)l * R * H;
  float acc = 0.f;
  for (int k = 0; k < R; ++k) acc = fmaf(re[k], wp[k * H + lane], acc);
  float v = acc * att[(size_t)l * 3 * H + 2 * H + lane];
  #pragma unroll
  for (int o = 32; o >= 1; o >>= 1) v += __shfl_xor(v, o);
  if (lane == 0) erel[l * NRELS + r] = v;
}

// pull aggregation + finalize, wave per node (unchanged from R5)
__global__ __launch_bounds__(256) void k_agg(const int* __restrict__ row,
    const int2* __restrict__ erec, const float* __restrict__ esrc,
    const float* __restrict__ edst, const float* __restrict__ erel,
    const float* __restrict__ hw, const float* __restrict__ h,
    const float* __restrict__ bias, const float* __restrict__ ln_g,
    const float* __restrict__ ln_b, float* __restrict__ hout, int N) {
  __shared__ float er[NRELS];
  __shared__ float els[4][DEGCAP];
  __shared__ int   sls[4][DEGCAP];
  if (threadIdx.x < NRELS) er[threadIdx.x] = erel[threadIdx.x];
  __syncthreads();
  int wid = threadIdx.x >> 6, lane = threadIdx.x & 63;
  int w = blockIdx.x * 4 + wid;
  if (w >= N) return;
  int st = row[w], en = row[w + 1];
  int deg = en - st;
  float ed = edst[w];
  float m = -3.4e38f;
  float acc = 0.f, ssum = 0.f;

  if (deg <= DEGCAP) {
    for (int j = st + lane; j < en; j += 64) {
      int2 r = erec[j];
      int sj = r.x & 0xFFFFF;
      float e = ed + esrc[sj] + er[(r.x >> 20) & 7];
      e = e > 0.f ? e : 0.2f * e;
      e += __int_as_float(r.y);
      els[wid][j - st] = e;
      sls[wid][j - st] = sj;
      m = fmaxf(m, e);
    }
    #pragma unroll
    for (int o = 32; o >= 1; o >>= 1) m = fmaxf(m, __shfl_xor(m, o));
    int k = 0;
    for (; k + 4 <= deg; k += 4) {
      int s0 = sls[wid][k], s1 = sls[wid][k + 1];
      int s2 = sls[wid][k + 2], s3 = sls[wid][k + 3];
      float h0 = hw[(size_t)s0 * H + lane];
      float h1 = hw[(size_t)s1 * H + lane];
      float h2 = hw[(size_t)s2 * H + lane];
      float h3 = hw[(size_t)s3 * H + lane];
      float p0 = __expf(els[wid][k] - m);
      float p1 = __expf(els[wid][k + 1] - m);
      float p2 = __expf(els[wid][k + 2] - m);
      float p3 = __expf(els[wid][k + 3] - m);
      ssum += p0; acc = fmaf(h0, p0, acc);
      ssum += p1; acc = fmaf(h1, p1, acc);
      ssum += p2; acc = fmaf(h2, p2, acc);
      ssum += p3; acc = fmaf(h3, p3, acc);
    }
    for (; k < deg; ++k) {
      int sj = sls[wid][k];
      float hv = hw[(size_t)sj * H + lane];
      float p = __expf(els[wid][k] - m);
      ssum += p; acc = fmaf(hv, p, acc);
    }
  } else {
    for (int j = st + lane; j < en; j += 64) {
      int2 r = erec[j];
      float e = ed + esrc[r.x & 0xFFFFF] + er[(r.x >> 20) & 7];
      e = e > 0.f ? e : 0.2f * e;
      m = fmaxf(m, e + __int_as_float(r.y));
    }
    #pragma unroll
    for (int o = 32; o >= 1; o >>= 1) m = fmaxf(m, __shfl_xor(m, o));
    for (int j = st; j < en; ++j) {
      int2 r = erec[j];
      int sj = r.x & 0xFFFFF;
      float e = ed + esrc[sj] + er[(r.x >> 20) & 7];
      e = e > 0.f ? e : 0.2f * e;
      e += __int_as_float(r.y);
      float p = __expf(e - m);
      ssum += p;
      acc = fmaf(hw[(size_t)sj * H + lane], p, acc);
    }
  }

  float o = (deg > 0) ? acc / ssum : 0.f;
  o += bias[lane];
  float v = h[(size_t)w * H + lane] + fmaxf(o, 0.f);
  float mu = v;
  #pragma unroll
  for (int off = 32; off >= 1; off >>= 1) mu += __shfl_xor(mu, off);
  mu *= (1.f / 64.f);
  float dv = v - mu;
  float var = dv * dv;
  #pragma unroll
  for (int off = 32; off >= 1; off >>= 1) var += __shfl_xor(var, off);
  var *= (1.f / 64.f);
  hout[(size_t)w * H + lane] = dv * rsqrtf(var + 1e-5f) * ln_g[lane] + ln_b[lane];
}

extern "C" void kernel_launch(void* const* d_in, const int* in_sizes, int n_in,
                              void* d_out, int out_size, void* d_ws, size_t ws_size,
                              hipStream_t stream) {
  const float* x       = (const float*)d_in[0];
  const float* W_in    = (const float*)d_in[1];
  const float* b_in    = (const float*)d_in[2];
  const float* W_msg   = (const float*)d_in[3];
  const float* rel_emb = (const float*)d_in[4];
  const float* W_rp    = (const float*)d_in[5];
  const float* att     = (const float*)d_in[6];
  const float* bias    = (const float*)d_in[7];
  const float* ln_g    = (const float*)d_in[8];
  const float* ln_b    = (const float*)d_in[9];
  const float* ea      = (const float*)d_in[10];
  const int*   ei      = (const int*)d_in[11];
  const int*   et      = (const int*)d_in[12];

  int N = in_sizes[0] / IN_DIM;
  int E = in_sizes[12];
  int L = in_sizes[7] / H;
  int R = in_sizes[5] / (L * H);   // 16
  int nb = (N + SCAN_B - 1) / SCAN_B;

  // bucket config: nbuck <= MAXBUCK
  int bshift = 9;
  while (((N + (1 << bshift) - 1) >> bshift) > MAXBUCK) bshift++;
  int nbuck = (N + (1 << bshift) - 1) >> bshift;
  int nwg = (E + CHUNK - 1) / CHUNK;
  int M = nbuck * nwg;
  int nb2 = (M + SCAN_B - 1) / SCAN_B;

  float* ws   = (float*)d_ws;
  float* h    = ws;                          // N*H
  float* hw   = h + (size_t)N * H;           // N*H floats; staged overlays it
  int4* staged = (int4*)hw;                  // E int4 = E*16 B (<= N*H*4 B here)
  size_t hwElems = (size_t)N * H;
  size_t stagedElems = ((size_t)E * 4 + 3) & ~(size_t)3;  // in floats, 16B-mult
  size_t region2 = hwElems > stagedElems ? hwElems : stagedElems;
  int2*  erec = (int2*)(hw + region2);       // E
  float* esrc = (float*)(erec + E);          // N
  float* edst = esrc + N;                    // N
  float* erel = edst + N;                    // L*NRELS
  int* row    = (int*)(erel + L * NRELS);    // N+1
  int* cursor = row + N + 1;                 // N
  int* deg    = cursor + N;                  // N
  int* inc    = deg + N;                     // N
  int* bsum   = inc + N;                     // nb
  int* counts = bsum + nb;                   // M
  int* cinc   = counts + M;                  // M
  int* woff   = cinc + M;                    // M
  int* bsum2  = woff + M;                    // nb2

  int nb16 = (N + 15) / 16;
  k_input<<<nb16, 256, 0, stream>>>(x, W_in, b_in, h, N);

  // node-degree CSR offsets
  hipMemsetAsync(deg, 0, (size_t)N * sizeof(int), stream);
  k_hist<<<(E + 255) / 256, 256, 0, stream>>>(ei, deg, E);
  k_scan1<<<nb, SCAN_B, 0, stream>>>(deg, inc, bsum, N);
  k_scan2<<<1, SCAN_B, 0, stream>>>(bsum, nb);
  k_scan3<<<nb, SCAN_B, 0, stream>>>(inc, bsum, deg, row, cursor, N);

  // binned two-pass scatter
  k_bhist<<<nwg, 256, 0, stream>>>(ei, counts, E, nwg, nbuck, bshift);
  k_scan1<<<nb2, SCAN_B, 0, stream>>>(counts, cinc, bsum2, M);
  k_scan2<<<1, SCAN_B, 0, stream>>>(bsum2, nb2);
  k_scan3b<<<nb2, SCAN_B, 0, stream>>>(cinc, bsum2, counts, woff, M);
  k_binscat<<<nwg, 256, 0, stream>>>(ei, et, ea, woff, staged, E, nwg, nbuck, bshift);
  k_scat2<<<nbuck, 256, 0, stream>>>(staged, woff, cursor, erec, E, nwg, nbuck);

  k_rel<<<L, 512, 0, stream>>>(rel_emb, W_rp, att, erel, R);

  for (int l = 0; l < L; ++l) {
    k_node<<<nb16, 256, 0, stream>>>(h, W_msg + (size_t)l * H * H,
                                     att + (size_t)l * 3 * H, hw, esrc, edst, N);
    float* hout = (l == L - 1) ? (float*)d_out : h;
    k_agg<<<(N + 3) / 4, 256, 0, stream>>>(row, erec, esrc, edst,
                                           erel + (size_t)l * NRELS, hw, h,
                                           bias + (size_t)l * H,
                                           ln_g + (size_t)l * H,
                                           ln_b + (size_t)l * H, hout, N);
  }
}

// Round 7
// 488.539 us; speedup vs baseline: 2.9285x; 1.1949x over previous
//
#include <hip/hip_runtime.h>
#include <math.h>

#define H 64
#define IN_DIM 128
#define NRELS 8
#define SCAN_B 512
#define DEGCAP 128
#define CHUNK 8192
#define MAXBUCK 512
#define BUCKSZ 2048   // max nodes per bucket (LDS arrays); N <= MAXBUCK*BUCKSZ

// ---- h0 = relu(x @ W_in + b_in). 16 nodes/block, 4 nodes/wave ----
__global__ __launch_bounds__(256) void k_input(const float* __restrict__ x,
    const float* __restrict__ W_in, const float* __restrict__ b_in,
    float* __restrict__ h, int N) {
  __shared__ __align__(16) float Ws[IN_DIM * H];   // 32 KB
  __shared__ __align__(16) float xs[16 * IN_DIM];  // 8 KB
  const float4* W4 = (const float4*)W_in;
  float4* Ws4 = (float4*)Ws;
  for (int i = threadIdx.x; i < IN_DIM * H / 4; i += 256) Ws4[i] = W4[i];
  int base = blockIdx.x * 16;
  const float4* x4 = (const float4*)x;
  float4* xs4 = (float4*)xs;
  for (int i = threadIdx.x; i < 16 * IN_DIM / 4; i += 256) {
    int nn = base + (i >> 5);   // 32 float4 per row
    xs4[i] = (nn < N) ? x4[(size_t)nn * 32 + (i & 31)]
                      : make_float4(0.f, 0.f, 0.f, 0.f);
  }
  __syncthreads();
  int wid = threadIdx.x >> 6, lane = threadIdx.x & 63;
  int n0 = base + wid * 4;
  float a0 = 0.f, a1 = 0.f, a2 = 0.f, a3 = 0.f;
  const float4* xr4 = (const float4*)(xs + wid * 4 * IN_DIM);
  #pragma unroll 4
  for (int kq = 0; kq < IN_DIM / 4; ++kq) {
    float4 f0 = xr4[kq];
    float4 f1 = xr4[32 + kq];
    float4 f2 = xr4[64 + kq];
    float4 f3 = xr4[96 + kq];
    int k = kq * 4;
    float w0 = Ws[(k + 0) * H + lane];
    float w1 = Ws[(k + 1) * H + lane];
    float w2 = Ws[(k + 2) * H + lane];
    float w3 = Ws[(k + 3) * H + lane];
    a0 = fmaf(f0.x, w0, a0); a0 = fmaf(f0.y, w1, a0);
    a0 = fmaf(f0.z, w2, a0); a0 = fmaf(f0.w, w3, a0);
    a1 = fmaf(f1.x, w0, a1); a1 = fmaf(f1.y, w1, a1);
    a1 = fmaf(f1.z, w2, a1); a1 = fmaf(f1.w, w3, a1);
    a2 = fmaf(f2.x, w0, a2); a2 = fmaf(f2.y, w1, a2);
    a2 = fmaf(f2.z, w2, a2); a2 = fmaf(f2.w, w3, a2);
    a3 = fmaf(f3.x, w0, a3); a3 = fmaf(f3.y, w1, a3);
    a3 = fmaf(f3.z, w2, a3); a3 = fmaf(f3.w, w3, a3);
  }
  float bb = b_in[lane];
  if (n0 + 0 < N) h[(size_t)(n0 + 0) * H + lane] = fmaxf(a0 + bb, 0.f);
  if (n0 + 1 < N) h[(size_t)(n0 + 1) * H + lane] = fmaxf(a1 + bb, 0.f);
  if (n0 + 2 < N) h[(size_t)(n0 + 2) * H + lane] = fmaxf(a2 + bb, 0.f);
  if (n0 + 3 < N) h[(size_t)(n0 + 3) * H + lane] = fmaxf(a3 + bb, 0.f);
}

// ---- scan machinery ----
__global__ __launch_bounds__(SCAN_B) void k_scan1(const int* __restrict__ deg,
    int* __restrict__ inc, int* __restrict__ bsum, int N) {
  __shared__ int sm[SCAN_B];
  int g = blockIdx.x * SCAN_B + threadIdx.x;
  sm[threadIdx.x] = (g < N) ? deg[g] : 0;
  __syncthreads();
  for (int o = 1; o < SCAN_B; o <<= 1) {
    int t = (threadIdx.x >= o) ? sm[threadIdx.x - o] : 0;
    __syncthreads();
    sm[threadIdx.x] += t;
    __syncthreads();
  }
  if (g < N) inc[g] = sm[threadIdx.x];
  if (threadIdx.x == SCAN_B - 1) bsum[blockIdx.x] = sm[threadIdx.x];
}

__global__ __launch_bounds__(SCAN_B) void k_scan2(int* __restrict__ bsum, int nb) {
  __shared__ int sm[SCAN_B];
  __shared__ int carry;
  if (threadIdx.x == 0) carry = 0;
  __syncthreads();
  for (int base = 0; base < nb; base += SCAN_B) {
    int i = base + threadIdx.x;
    sm[threadIdx.x] = (i < nb) ? bsum[i] : 0;
    __syncthreads();
    if (threadIdx.x == 0) {
      int run = carry;
      int lim = nb - base < SCAN_B ? nb - base : SCAN_B;
      for (int j = 0; j < lim; ++j) { run += sm[j]; sm[j] = run; }
      carry = run;
    }
    __syncthreads();
    if (i < nb) bsum[i] = sm[threadIdx.x];
    __syncthreads();
  }
}

// row from inclusive node-degree scan
__global__ __launch_bounds__(SCAN_B) void k_scan3(const int* __restrict__ inc,
    const int* __restrict__ bsum, const int* __restrict__ deg,
    int* __restrict__ row, int N) {
  int g = blockIdx.x * SCAN_B + threadIdx.x;
  if (g >= N) return;
  int off = (blockIdx.x > 0) ? bsum[blockIdx.x - 1] : 0;
  int end = inc[g] + off;
  row[g] = end - deg[g];
  if (g == N - 1) row[N] = end;
}

// exclusive scan output for the (bin,wg) counts matrix
__global__ __launch_bounds__(SCAN_B) void k_scan3b(const int* __restrict__ inc,
    const int* __restrict__ bsum, const int* __restrict__ cnt,
    int* __restrict__ woff, int M) {
  int g = blockIdx.x * SCAN_B + threadIdx.x;
  if (g >= M) return;
  int off = (blockIdx.x > 0) ? bsum[blockIdx.x - 1] : 0;
  woff[g] = inc[g] + off - cnt[g];
}

// per-wg histogram of dst buckets: counts[bin*nwg + wg]
__global__ __launch_bounds__(256) void k_bhist(const int* __restrict__ ei,
    int* __restrict__ counts, int E, int nwg, int nbuck, int bshift) {
  __shared__ int cnt[MAXBUCK];
  for (int b = threadIdx.x; b < nbuck; b += 256) cnt[b] = 0;
  __syncthreads();
  int wg = blockIdx.x;
  int lo = wg * CHUNK, hi = lo + CHUNK < E ? lo + CHUNK : E;
  for (int j = lo + threadIdx.x; j < hi; j += 256)
    atomicAdd(&cnt[ei[E + j] >> bshift], 1);
  __syncthreads();
  for (int b = threadIdx.x; b < nbuck; b += 256)
    counts[(size_t)b * nwg + wg] = cnt[b];
}

// binned scatter: each wg appends into its private per-bin windows
__global__ __launch_bounds__(256) void k_binscat(const int* __restrict__ ei,
    const int* __restrict__ et, const float* __restrict__ ea,
    const int* __restrict__ woff, int4* __restrict__ staged,
    int E, int nwg, int nbuck, int bshift) {
  __shared__ int cur[MAXBUCK];
  int wg = blockIdx.x;
  for (int b = threadIdx.x; b < nbuck; b += 256)
    cur[b] = woff[(size_t)b * nwg + wg];
  __syncthreads();
  int lo = wg * CHUNK, hi = lo + CHUNK < E ? lo + CHUNK : E;
  for (int j = lo + threadIdx.x; j < hi; j += 256) {
    int s = ei[j], d = ei[E + j];
    int t = et[j]; t = t < 0 ? 0 : (t > NRELS - 1 ? NRELS - 1 : t);
    float cl = 0.1f * logf(fmaxf(ea[j], 1e-6f));
    int pos = atomicAdd(&cur[d >> bshift], 1);
    staged[pos] = make_int4(s | (t << 20), d, __float_as_int(cl), 0);
  }
}

// per-bucket degree histogram in LDS (no global atomics); also zero-fills deg
__global__ __launch_bounds__(256) void k_hist2(const int* __restrict__ staged,
    const int* __restrict__ woff, int* __restrict__ deg,
    int E, int nwg, int nbuck, int bshift, int N) {
  __shared__ int cnt[BUCKSZ];
  int b = blockIdx.x;
  int nbase = b << bshift;
  int nn = N - nbase; if (nn > (1 << bshift)) nn = 1 << bshift;
  for (int i = threadIdx.x; i < nn; i += 256) cnt[i] = 0;
  __syncthreads();
  int lo = woff[(size_t)b * nwg];
  int hi = (b + 1 < nbuck) ? woff[(size_t)(b + 1) * nwg] : E;
  for (int j = lo + threadIdx.x; j < hi; j += 256)
    atomicAdd(&cnt[staged[j * 4 + 1] - nbase], 1);
  __syncthreads();
  for (int i = threadIdx.x; i < nn; i += 256) deg[nbase + i] = cnt[i];
}

// bucket -> exact CSR position; cursors live in LDS
__global__ __launch_bounds__(256) void k_scat2(const int4* __restrict__ staged,
    const int* __restrict__ woff, const int* __restrict__ row,
    int2* __restrict__ erec, int E, int nwg, int nbuck, int bshift, int N) {
  __shared__ int cur[BUCKSZ];
  int b = blockIdx.x;
  int nbase = b << bshift;
  int nn = N - nbase; if (nn > (1 << bshift)) nn = 1 << bshift;
  for (int i = threadIdx.x; i < nn; i += 256) cur[i] = row[nbase + i];
  __syncthreads();
  int lo = woff[(size_t)b * nwg];
  int hi = (b + 1 < nbuck) ? woff[(size_t)(b + 1) * nwg] : E;
  for (int j = lo + threadIdx.x; j < hi; j += 256) {
    int4 r = staged[j];
    int pos = atomicAdd(&cur[r.y - nbase], 1);
    erec[pos] = make_int2(r.x, r.z);
  }
}

// ---- per-layer ----
__global__ __launch_bounds__(256) void k_node(const float* __restrict__ h,
    const float* __restrict__ Wmsg, const float* __restrict__ att,
    float* __restrict__ hw, float* __restrict__ esrc, float* __restrict__ edst,
    int N) {
  __shared__ __align__(16) float Ws[H * H];   // 16 KB
  __shared__ __align__(16) float hs[16 * H];  // 4 KB
  const float4* W4 = (const float4*)Wmsg;
  float4* Ws4 = (float4*)Ws;
  for (int i = threadIdx.x; i < H * H / 4; i += 256) Ws4[i] = W4[i];
  int base = blockIdx.x * 16;
  const float4* h4 = (const float4*)h;
  float4* hs4 = (float4*)hs;
  for (int i = threadIdx.x; i < 16 * H / 4; i += 256) {
    int nn = base + (i >> 4);   // 16 float4 per row
    hs4[i] = (nn < N) ? h4[(size_t)nn * 16 + (i & 15)]
                      : make_float4(0.f, 0.f, 0.f, 0.f);
  }
  __syncthreads();
  int wid = threadIdx.x >> 6, lane = threadIdx.x & 63;
  int n0 = base + wid * 4;
  float a0 = 0.f, a1 = 0.f, a2 = 0.f, a3 = 0.f;
  const float4* hr4 = (const float4*)(hs + wid * 4 * H);
  #pragma unroll 4
  for (int kq = 0; kq < H / 4; ++kq) {
    float4 f0 = hr4[kq];
    float4 f1 = hr4[16 + kq];
    float4 f2 = hr4[32 + kq];
    float4 f3 = hr4[48 + kq];
    int k = kq * 4;
    float w0 = Ws[(k + 0) * H + lane];
    float w1 = Ws[(k + 1) * H + lane];
    float w2 = Ws[(k + 2) * H + lane];
    float w3 = Ws[(k + 3) * H + lane];
    a0 = fmaf(f0.x, w0, a0); a0 = fmaf(f0.y, w1, a0);
    a0 = fmaf(f0.z, w2, a0); a0 = fmaf(f0.w, w3, a0);
    a1 = fmaf(f1.x, w0, a1); a1 = fmaf(f1.y, w1, a1);
    a1 = fmaf(f1.z, w2, a1); a1 = fmaf(f1.w, w3, a1);
    a2 = fmaf(f2.x, w0, a2); a2 = fmaf(f2.y, w1, a2);
    a2 = fmaf(f2.z, w2, a2); a2 = fmaf(f2.w, w3, a2);
    a3 = fmaf(f3.x, w0, a3); a3 = fmaf(f3.y, w1, a3);
    a3 = fmaf(f3.z, w2, a3); a3 = fmaf(f3.w, w3, a3);
  }
  float ad = att[lane], as = att[H + lane];
  float acc[4] = {a0, a1, a2, a3};
  #pragma unroll
  for (int i = 0; i < 4; ++i) {
    int n = n0 + i;
    if (n >= N) break;
    hw[(size_t)n * H + lane] = acc[i];
    float vd = acc[i] * ad, vs = acc[i] * as;
    #pragma unroll
    for (int o = 32; o >= 1; o >>= 1) {
      vd += __shfl_xor(vd, o);
      vs += __shfl_xor(vs, o);
    }
    if (lane == 0) { edst[n] = vd; esrc[n] = vs; }
  }
}

__global__ void k_rel(const float* __restrict__ rel_emb,
    const float* __restrict__ Wrp, const float* __restrict__ att,
    float* __restrict__ erel, int R) {
  int l = blockIdx.x;
  int r = threadIdx.x >> 6, lane = threadIdx.x & 63;
  const float* re = rel_emb + ((size_t)l * NRELS + r) * R;
  const float* wp = Wrp + (size_t)l * R * H;
  float acc = 0.f;
  for (int k = 0; k < R; ++k) acc = fmaf(re[k], wp[k * H + lane], acc);
  float v = acc * att[(size_t)l * 3 * H + 2 * H + lane];
  #pragma unroll
  for (int o = 32; o >= 1; o >>= 1) v += __shfl_xor(v, o);
  if (lane == 0) erel[l * NRELS + r] = v;
}

// pull aggregation + finalize, wave per node; 8-deep gather pipeline
__global__ __launch_bounds__(256) void k_agg(const int* __restrict__ row,
    const int2* __restrict__ erec, const float* __restrict__ esrc,
    const float* __restrict__ edst, const float* __restrict__ erel,
    const float* __restrict__ hw, const float* __restrict__ h,
    const float* __restrict__ bias, const float* __restrict__ ln_g,
    const float* __restrict__ ln_b, float* __restrict__ hout, int N) {
  __shared__ float er[NRELS];
  __shared__ float els[4][DEGCAP];
  __shared__ int   sls[4][DEGCAP];
  if (threadIdx.x < NRELS) er[threadIdx.x] = erel[threadIdx.x];
  __syncthreads();
  int wid = threadIdx.x >> 6, lane = threadIdx.x & 63;
  int w = blockIdx.x * 4 + wid;
  if (w >= N) return;
  int st = row[w], en = row[w + 1];
  int deg = en - st;
  float ed = edst[w];
  float m = -3.4e38f;
  float acc = 0.f, ssum = 0.f;

  if (deg <= DEGCAP) {
    for (int j = st + lane; j < en; j += 64) {
      int2 r = erec[j];
      int sj = r.x & 0xFFFFF;
      float e = ed + esrc[sj] + er[(r.x >> 20) & 7];
      e = e > 0.f ? e : 0.2f * e;
      e += __int_as_float(r.y);
      els[wid][j - st] = e;
      sls[wid][j - st] = sj;
      m = fmaxf(m, e);
    }
    #pragma unroll
    for (int o = 32; o >= 1; o >>= 1) m = fmaxf(m, __shfl_xor(m, o));
    int k = 0;
    for (; k + 8 <= deg; k += 8) {
      int s0 = sls[wid][k],     s1 = sls[wid][k + 1];
      int s2 = sls[wid][k + 2], s3 = sls[wid][k + 3];
      int s4 = sls[wid][k + 4], s5 = sls[wid][k + 5];
      int s6 = sls[wid][k + 6], s7 = sls[wid][k + 7];
      float h0 = hw[(size_t)s0 * H + lane];
      float h1 = hw[(size_t)s1 * H + lane];
      float h2 = hw[(size_t)s2 * H + lane];
      float h3 = hw[(size_t)s3 * H + lane];
      float h4 = hw[(size_t)s4 * H + lane];
      float h5 = hw[(size_t)s5 * H + lane];
      float h6 = hw[(size_t)s6 * H + lane];
      float h7 = hw[(size_t)s7 * H + lane];
      float p0 = __expf(els[wid][k] - m);
      float p1 = __expf(els[wid][k + 1] - m);
      float p2 = __expf(els[wid][k + 2] - m);
      float p3 = __expf(els[wid][k + 3] - m);
      float p4 = __expf(els[wid][k + 4] - m);
      float p5 = __expf(els[wid][k + 5] - m);
      float p6 = __expf(els[wid][k + 6] - m);
      float p7 = __expf(els[wid][k + 7] - m);
      ssum += p0; acc = fmaf(h0, p0, acc);
      ssum += p1; acc = fmaf(h1, p1, acc);
      ssum += p2; acc = fmaf(h2, p2, acc);
      ssum += p3; acc = fmaf(h3, p3, acc);
      ssum += p4; acc = fmaf(h4, p4, acc);
      ssum += p5; acc = fmaf(h5, p5, acc);
      ssum += p6; acc = fmaf(h6, p6, acc);
      ssum += p7; acc = fmaf(h7, p7, acc);
    }
    for (; k + 4 <= deg; k += 4) {
      int s0 = sls[wid][k],     s1 = sls[wid][k + 1];
      int s2 = sls[wid][k + 2], s3 = sls[wid][k + 3];
      float h0 = hw[(size_t)s0 * H + lane];
      float h1 = hw[(size_t)s1 * H + lane];
      float h2 = hw[(size_t)s2 * H + lane];
      float h3 = hw[(size_t)s3 * H + lane];
      float p0 = __expf(els[wid][k] - m);
      float p1 = __expf(els[wid][k + 1] - m);
      float p2 = __expf(els[wid][k + 2] - m);
      float p3 = __expf(els[wid][k + 3] - m);
      ssum += p0; acc = fmaf(h0, p0, acc);
      ssum += p1; acc = fmaf(h1, p1, acc);
      ssum += p2; acc = fmaf(h2, p2, acc);
      ssum += p3; acc = fmaf(h3, p3, acc);
    }
    for (; k < deg; ++k) {
      int sj = sls[wid][k];
      float hv = hw[(size_t)sj * H + lane];
      float p = __expf(els[wid][k] - m);
      ssum += p; acc = fmaf(hv, p, acc);
    }
  } else {
    for (int j = st + lane; j < en; j += 64) {
      int2 r = erec[j];
      float e = ed + esrc[r.x & 0xFFFFF] + er[(r.x >> 20) & 7];
      e = e > 0.f ? e : 0.2f * e;
      m = fmaxf(m, e + __int_as_float(r.y));
    }
    #pragma unroll
    for (int o = 32; o >= 1; o >>= 1) m = fmaxf(m, __shfl_xor(m, o));
    for (int j = st; j < en; ++j) {
      int2 r = erec[j];
      int sj = r.x & 0xFFFFF;
      float e = ed + esrc[sj] + er[(r.x >> 20) & 7];
      e = e > 0.f ? e : 0.2f * e;
      e += __int_as_float(r.y);
      float p = __expf(e - m);
      ssum += p;
      acc = fmaf(hw[(size_t)sj * H + lane], p, acc);
    }
  }

  float o = (deg > 0) ? acc / ssum : 0.f;
  o += bias[lane];
  float v = h[(size_t)w * H + lane] + fmaxf(o, 0.f);
  float mu = v;
  #pragma unroll
  for (int off = 32; off >= 1; off >>= 1) mu += __shfl_xor(mu, off);
  mu *= (1.f / 64.f);
  float dv = v - mu;
  float var = dv * dv;
  #pragma unroll
  for (int off = 32; off >= 1; off >>= 1) var += __shfl_xor(var, off);
  var *= (1.f / 64.f);
  hout[(size_t)w * H + lane] = dv * rsqrtf(var + 1e-5f) * ln_g[lane] + ln_b[lane];
}

extern "C" void kernel_launch(void* const* d_in, const int* in_sizes, int n_in,
                              void* d_out, int out_size, void* d_ws, size_t ws_size,
                              hipStream_t stream) {
  const float* x       = (const float*)d_in[0];
  const float* W_in    = (const float*)d_in[1];
  const float* b_in    = (const float*)d_in[2];
  const float* W_msg   = (const float*)d_in[3];
  const float* rel_emb = (const float*)d_in[4];
  const float* W_rp    = (const float*)d_in[5];
  const float* att     = (const float*)d_in[6];
  const float* bias    = (const float*)d_in[7];
  const float* ln_g    = (const float*)d_in[8];
  const float* ln_b    = (const float*)d_in[9];
  const float* ea      = (const float*)d_in[10];
  const int*   ei      = (const int*)d_in[11];
  const int*   et      = (const int*)d_in[12];

  int N = in_sizes[0] / IN_DIM;
  int E = in_sizes[12];
  int L = in_sizes[7] / H;
  int R = in_sizes[5] / (L * H);   // 16
  int nb = (N + SCAN_B - 1) / SCAN_B;

  int bshift = 9;
  while (((N + (1 << bshift) - 1) >> bshift) > MAXBUCK) bshift++;
  int nbuck = (N + (1 << bshift) - 1) >> bshift;
  int nwg = (E + CHUNK - 1) / CHUNK;
  int M = nbuck * nwg;
  int nb2 = (M + SCAN_B - 1) / SCAN_B;

  float* ws   = (float*)d_ws;
  float* h    = ws;                          // N*H
  float* hw   = h + (size_t)N * H;           // N*H floats; staged overlays it
  int4* staged = (int4*)hw;                  // E int4
  size_t hwElems = (size_t)N * H;
  size_t stagedElems = ((size_t)E * 4 + 3) & ~(size_t)3;
  size_t region2 = hwElems > stagedElems ? hwElems : stagedElems;
  int2*  erec = (int2*)(hw + region2);       // E
  float* esrc = (float*)(erec + E);          // N
  float* edst = esrc + N;                    // N
  float* erel = edst + N;                    // L*NRELS
  int* row    = (int*)(erel + L * NRELS);    // N+1
  int* deg    = row + N + 1;                 // N
  int* inc    = deg + N;                     // N
  int* bsum   = inc + N;                     // nb
  int* counts = bsum + nb;                   // M
  int* cinc   = counts + M;                  // M
  int* woff   = cinc + M;                    // M
  int* bsum2  = woff + M;                    // nb2

  int nb16 = (N + 15) / 16;
  k_input<<<nb16, 256, 0, stream>>>(x, W_in, b_in, h, N);

  // binned two-pass scatter (bucket-sorted staging)
  k_bhist<<<nwg, 256, 0, stream>>>(ei, counts, E, nwg, nbuck, bshift);
  k_scan1<<<nb2, SCAN_B, 0, stream>>>(counts, cinc, bsum2, M);
  k_scan2<<<1, SCAN_B, 0, stream>>>(bsum2, nb2);
  k_scan3b<<<nb2, SCAN_B, 0, stream>>>(cinc, bsum2, counts, woff, M);
  k_binscat<<<nwg, 256, 0, stream>>>(ei, et, ea, woff, staged, E, nwg, nbuck, bshift);

  // node degrees from bucket-local LDS histograms, then CSR offsets
  k_hist2<<<nbuck, 256, 0, stream>>>((const int*)staged, woff, deg, E, nwg, nbuck, bshift, N);
  k_scan1<<<nb, SCAN_B, 0, stream>>>(deg, inc, bsum, N);
  k_scan2<<<1, SCAN_B, 0, stream>>>(bsum, nb);
  k_scan3<<<nb, SCAN_B, 0, stream>>>(inc, bsum, deg, row, N);
  k_scat2<<<nbuck, 256, 0, stream>>>(staged, woff, row, erec, E, nwg, nbuck, bshift, N);

  k_rel<<<L, 512, 0, stream>>>(rel_emb, W_rp, att, erel, R);

  for (int l = 0; l < L; ++l) {
    k_node<<<nb16, 256, 0, stream>>>(h, W_msg + (size_t)l * H * H,
                                     att + (size_t)l * 3 * H, hw, esrc, edst, N);
    float* hout = (l == L - 1) ? (float*)d_out : h;
    k_agg<<<(N + 3) / 4, 256, 0, stream>>>(row, erec, esrc, edst,
                                           erel + (size_t)l * NRELS, hw, h,
                                           bias + (size_t)l * H,
                                           ln_g + (size_t)l * H,
                                           ln_b + (size_t)l * H, hout, N);
  }
}

// Round 8
// 451.826 us; speedup vs baseline: 3.1665x; 1.0813x over previous
//
#include <hip/hip_runtime.h>
#include <math.h>

#define H 64
#define IN_DIM 128
#define NRELS 8
#define SCAN_B 512
#define DEGCAP 128
#define CHUNK 8192
#define MAXBUCK 512
#define BUCKSZ 2048

// wdst[l][k] = W_msg[l][k,:] . a_dst[l] ; wsrc likewise (logit projection vectors)
__global__ void k_wvec(const float* __restrict__ Wmsg, const float* __restrict__ att,
                       float* __restrict__ wdst, float* __restrict__ wsrc) {
  int l = blockIdx.x, k = threadIdx.x;
  const float* W  = Wmsg + ((size_t)l * H + k) * H;
  const float* ad = att + (size_t)l * 3 * H;
  const float* as = ad + H;
  float sd = 0.f, ss = 0.f;
  for (int j = 0; j < H; ++j) { float w = W[j]; sd = fmaf(w, ad[j], sd); ss = fmaf(w, as[j], ss); }
  wdst[l * H + k] = sd;
  wsrc[l * H + k] = ss;
}

// ---- h0 = relu(x @ W_in + b_in) + layer-0 esrc/edst. 16 nodes/block ----
__global__ __launch_bounds__(256) void k_input(const float* __restrict__ x,
    const float* __restrict__ W_in, const float* __restrict__ b_in,
    const float* __restrict__ wsrc0, const float* __restrict__ wdst0,
    float* __restrict__ h, float* __restrict__ esrc, float* __restrict__ edst, int N) {
  __shared__ __align__(16) float Ws[IN_DIM * H];
  __shared__ __align__(16) float xs[16 * IN_DIM];
  const float4* W4 = (const float4*)W_in;
  float4* Ws4 = (float4*)Ws;
  for (int i = threadIdx.x; i < IN_DIM * H / 4; i += 256) Ws4[i] = W4[i];
  int base = blockIdx.x * 16;
  const float4* x4 = (const float4*)x;
  float4* xs4 = (float4*)xs;
  for (int i = threadIdx.x; i < 16 * IN_DIM / 4; i += 256) {
    int nn = base + (i >> 5);
    xs4[i] = (nn < N) ? x4[(size_t)nn * 32 + (i & 31)]
                      : make_float4(0.f, 0.f, 0.f, 0.f);
  }
  __syncthreads();
  int wid = threadIdx.x >> 6, lane = threadIdx.x & 63;
  int n0 = base + wid * 4;
  float a0 = 0.f, a1 = 0.f, a2 = 0.f, a3 = 0.f;
  const float4* xr4 = (const float4*)(xs + wid * 4 * IN_DIM);
  #pragma unroll 4
  for (int kq = 0; kq < IN_DIM / 4; ++kq) {
    float4 f0 = xr4[kq];
    float4 f1 = xr4[32 + kq];
    float4 f2 = xr4[64 + kq];
    float4 f3 = xr4[96 + kq];
    int k = kq * 4;
    float w0 = Ws[(k + 0) * H + lane];
    float w1 = Ws[(k + 1) * H + lane];
    float w2 = Ws[(k + 2) * H + lane];
    float w3 = Ws[(k + 3) * H + lane];
    a0 = fmaf(f0.x, w0, a0); a0 = fmaf(f0.y, w1, a0);
    a0 = fmaf(f0.z, w2, a0); a0 = fmaf(f0.w, w3, a0);
    a1 = fmaf(f1.x, w0, a1); a1 = fmaf(f1.y, w1, a1);
    a1 = fmaf(f1.z, w2, a1); a1 = fmaf(f1.w, w3, a1);
    a2 = fmaf(f2.x, w0, a2); a2 = fmaf(f2.y, w1, a2);
    a2 = fmaf(f2.z, w2, a2); a2 = fmaf(f2.w, w3, a2);
    a3 = fmaf(f3.x, w0, a3); a3 = fmaf(f3.y, w1, a3);
    a3 = fmaf(f3.z, w2, a3); a3 = fmaf(f3.w, w3, a3);
  }
  float bb = b_in[lane];
  float wsn = wsrc0[lane], wdn = wdst0[lane];
  float vals[4] = {fmaxf(a0 + bb, 0.f), fmaxf(a1 + bb, 0.f),
                   fmaxf(a2 + bb, 0.f), fmaxf(a3 + bb, 0.f)};
  #pragma unroll
  for (int i = 0; i < 4; ++i) {
    int n = n0 + i;
    if (n >= N) break;
    h[(size_t)n * H + lane] = vals[i];
    float vs = vals[i] * wsn, vd = vals[i] * wdn;
    #pragma unroll
    for (int o = 32; o >= 1; o >>= 1) {
      vs += __shfl_xor(vs, o);
      vd += __shfl_xor(vd, o);
    }
    if (lane == 0) { esrc[n] = vs; edst[n] = vd; }
  }
}

// ---- scan machinery ----
__global__ __launch_bounds__(SCAN_B) void k_scan1(const int* __restrict__ deg,
    int* __restrict__ inc, int* __restrict__ bsum, int N) {
  __shared__ int sm[SCAN_B];
  int g = blockIdx.x * SCAN_B + threadIdx.x;
  sm[threadIdx.x] = (g < N) ? deg[g] : 0;
  __syncthreads();
  for (int o = 1; o < SCAN_B; o <<= 1) {
    int t = (threadIdx.x >= o) ? sm[threadIdx.x - o] : 0;
    __syncthreads();
    sm[threadIdx.x] += t;
    __syncthreads();
  }
  if (g < N) inc[g] = sm[threadIdx.x];
  if (threadIdx.x == SCAN_B - 1) bsum[blockIdx.x] = sm[threadIdx.x];
}

__global__ __launch_bounds__(SCAN_B) void k_scan2(int* __restrict__ bsum, int nb) {
  __shared__ int sm[SCAN_B];
  __shared__ int carry;
  if (threadIdx.x == 0) carry = 0;
  __syncthreads();
  for (int base = 0; base < nb; base += SCAN_B) {
    int i = base + threadIdx.x;
    sm[threadIdx.x] = (i < nb) ? bsum[i] : 0;
    __syncthreads();
    if (threadIdx.x == 0) {
      int run = carry;
      int lim = nb - base < SCAN_B ? nb - base : SCAN_B;
      for (int j = 0; j < lim; ++j) { run += sm[j]; sm[j] = run; }
      carry = run;
    }
    __syncthreads();
    if (i < nb) bsum[i] = sm[threadIdx.x];
    __syncthreads();
  }
}

__global__ __launch_bounds__(SCAN_B) void k_scan3(const int* __restrict__ inc,
    const int* __restrict__ bsum, const int* __restrict__ deg,
    int* __restrict__ row, int N) {
  int g = blockIdx.x * SCAN_B + threadIdx.x;
  if (g >= N) return;
  int off = (blockIdx.x > 0) ? bsum[blockIdx.x - 1] : 0;
  int end = inc[g] + off;
  row[g] = end - deg[g];
  if (g == N - 1) row[N] = end;
}

__global__ __launch_bounds__(SCAN_B) void k_scan3b(const int* __restrict__ inc,
    const int* __restrict__ bsum, const int* __restrict__ cnt,
    int* __restrict__ woff, int M) {
  int g = blockIdx.x * SCAN_B + threadIdx.x;
  if (g >= M) return;
  int off = (blockIdx.x > 0) ? bsum[blockIdx.x - 1] : 0;
  woff[g] = inc[g] + off - cnt[g];
}

__global__ __launch_bounds__(256) void k_bhist(const int* __restrict__ ei,
    int* __restrict__ counts, int E, int nwg, int nbuck, int bshift) {
  __shared__ int cnt[MAXBUCK];
  for (int b = threadIdx.x; b < nbuck; b += 256) cnt[b] = 0;
  __syncthreads();
  int wg = blockIdx.x;
  int lo = wg * CHUNK, hi = lo + CHUNK < E ? lo + CHUNK : E;
  for (int j = lo + threadIdx.x; j < hi; j += 256)
    atomicAdd(&cnt[ei[E + j] >> bshift], 1);
  __syncthreads();
  for (int b = threadIdx.x; b < nbuck; b += 256)
    counts[(size_t)b * nwg + wg] = cnt[b];
}

__global__ __launch_bounds__(256) void k_binscat(const int* __restrict__ ei,
    const int* __restrict__ et, const float* __restrict__ ea,
    const int* __restrict__ woff, int4* __restrict__ staged,
    int E, int nwg, int nbuck, int bshift) {
  __shared__ int cur[MAXBUCK];
  int wg = blockIdx.x;
  for (int b = threadIdx.x; b < nbuck; b += 256)
    cur[b] = woff[(size_t)b * nwg + wg];
  __syncthreads();
  int lo = wg * CHUNK, hi = lo + CHUNK < E ? lo + CHUNK : E;
  for (int j = lo + threadIdx.x; j < hi; j += 256) {
    int s = ei[j], d = ei[E + j];
    int t = et[j]; t = t < 0 ? 0 : (t > NRELS - 1 ? NRELS - 1 : t);
    float cl = 0.1f * logf(fmaxf(ea[j], 1e-6f));
    int pos = atomicAdd(&cur[d >> bshift], 1);
    staged[pos] = make_int4(s | (t << 20), d, __float_as_int(cl), 0);
  }
}

__global__ __launch_bounds__(256) void k_hist2(const int* __restrict__ staged,
    const int* __restrict__ woff, int* __restrict__ deg,
    int E, int nwg, int nbuck, int bshift, int N) {
  __shared__ int cnt[BUCKSZ];
  int b = blockIdx.x;
  int nbase = b << bshift;
  int nn = N - nbase; if (nn > (1 << bshift)) nn = 1 << bshift;
  for (int i = threadIdx.x; i < nn; i += 256) cnt[i] = 0;
  __syncthreads();
  int lo = woff[(size_t)b * nwg];
  int hi = (b + 1 < nbuck) ? woff[(size_t)(b + 1) * nwg] : E;
  for (int j = lo + threadIdx.x; j < hi; j += 256)
    atomicAdd(&cnt[staged[j * 4 + 1] - nbase], 1);
  __syncthreads();
  for (int i = threadIdx.x; i < nn; i += 256) deg[nbase + i] = cnt[i];
}

__global__ __launch_bounds__(256) void k_scat2(const int4* __restrict__ staged,
    const int* __restrict__ woff, const int* __restrict__ row,
    int2* __restrict__ erec, int E, int nwg, int nbuck, int bshift, int N) {
  __shared__ int cur[BUCKSZ];
  int b = blockIdx.x;
  int nbase = b << bshift;
  int nn = N - nbase; if (nn > (1 << bshift)) nn = 1 << bshift;
  for (int i = threadIdx.x; i < nn; i += 256) cur[i] = row[nbase + i];
  __syncthreads();
  int lo = woff[(size_t)b * nwg];
  int hi = (b + 1 < nbuck) ? woff[(size_t)(b + 1) * nwg] : E;
  for (int j = lo + threadIdx.x; j < hi; j += 256) {
    int4 r = staged[j];
    int pos = atomicAdd(&cur[r.y - nbase], 1);
    erec[pos] = make_int2(r.x, r.z);
  }
}

__global__ void k_rel(const float* __restrict__ rel_emb,
    const float* __restrict__ Wrp, const float* __restrict__ att,
    float* __restrict__ erel, int R) {
  int l = blockIdx.x;
  int r = threadIdx.x >> 6, lane = threadIdx.x & 63;
  const float* re = rel_emb + ((size_t)l * NRELS + r) * R;
  const float* wp = Wrp + (size_t)l * R * H;
  float acc = 0.f;
  for (int k = 0; k < R; ++k) acc = fmaf(re[k], wp[k * H + lane], acc);
  float v = acc * att[(size_t)l * 3 * H + 2 * H + lane];
  #pragma unroll
  for (int o = 32; o >= 1; o >>= 1) v += __shfl_xor(v, o);
  if (lane == 0) erel[l * NRELS + r] = v;
}

// fused: pull-aggregate raw h, epilogue GEMM (@Wmsg), bias/relu/residual/LN,
// and next-layer esrc/edst. 16 nodes/block = 4 waves x 4 serial nodes.
__global__ __launch_bounds__(256) void k_agg(const int* __restrict__ row,
    const int2* __restrict__ erec, const float* __restrict__ esrc,
    const float* __restrict__ edst, const float* __restrict__ erel,
    const float* __restrict__ Wmsg, const float* __restrict__ hin,
    const float* __restrict__ bias, const float* __restrict__ ln_g,
    const float* __restrict__ ln_b,
    const float* __restrict__ wsrc_n, const float* __restrict__ wdst_n,
    float* __restrict__ esrc_o, float* __restrict__ edst_o,
    float* __restrict__ hout, int N, int last) {
  __shared__ float er[NRELS];
  __shared__ __align__(16) float Ws[H * H];     // 16 KB
  __shared__ __align__(16) float aggs[4][H];    // 1 KB
  __shared__ float els[4][DEGCAP];              // 2 KB
  __shared__ int   sls[4][DEGCAP];              // 2 KB
  const float4* W4 = (const float4*)Wmsg;
  float4* Ws4 = (float4*)Ws;
  for (int i = threadIdx.x; i < H * H / 4; i += 256) Ws4[i] = W4[i];
  if (threadIdx.x < NRELS) er[threadIdx.x] = erel[threadIdx.x];
  __syncthreads();
  int wid = threadIdx.x >> 6, lane = threadIdx.x & 63;
  float bb = bias[lane], lg = ln_g[lane], lb = ln_b[lane];
  float wsn = last ? 0.f : wsrc_n[lane];
  float wdn = last ? 0.f : wdst_n[lane];
  int base = blockIdx.x * 16 + wid * 4;

  for (int ii = 0; ii < 4; ++ii) {
    int w = base + ii;
    if (w >= N) break;
    int st = row[w], en = row[w + 1];
    int deg = en - st;
    float ed = edst[w];
    float m = -3.4e38f, agg = 0.f, ssum = 0.f;

    if (deg <= DEGCAP) {
      for (int j = st + lane; j < en; j += 64) {
        int2 r = erec[j];
        int sj = r.x & 0xFFFFF;
        float e = ed + esrc[sj] + er[(r.x >> 20) & 7];
        e = e > 0.f ? e : 0.2f * e;
        e += __int_as_float(r.y);
        els[wid][j - st] = e;
        sls[wid][j - st] = sj;
        m = fmaxf(m, e);
      }
      #pragma unroll
      for (int o = 32; o >= 1; o >>= 1) m = fmaxf(m, __shfl_xor(m, o));
      int k = 0;
      for (; k + 8 <= deg; k += 8) {
        int s0 = sls[wid][k],     s1 = sls[wid][k + 1];
        int s2 = sls[wid][k + 2], s3 = sls[wid][k + 3];
        int s4 = sls[wid][k + 4], s5 = sls[wid][k + 5];
        int s6 = sls[wid][k + 6], s7 = sls[wid][k + 7];
        float h0 = hin[(size_t)s0 * H + lane];
        float h1 = hin[(size_t)s1 * H + lane];
        float h2 = hin[(size_t)s2 * H + lane];
        float h3 = hin[(size_t)s3 * H + lane];
        float h4 = hin[(size_t)s4 * H + lane];
        float h5 = hin[(size_t)s5 * H + lane];
        float h6 = hin[(size_t)s6 * H + lane];
        float h7 = hin[(size_t)s7 * H + lane];
        float p0 = __expf(els[wid][k] - m);
        float p1 = __expf(els[wid][k + 1] - m);
        float p2 = __expf(els[wid][k + 2] - m);
        float p3 = __expf(els[wid][k + 3] - m);
        float p4 = __expf(els[wid][k + 4] - m);
        float p5 = __expf(els[wid][k + 5] - m);
        float p6 = __expf(els[wid][k + 6] - m);
        float p7 = __expf(els[wid][k + 7] - m);
        ssum += p0; agg = fmaf(h0, p0, agg);
        ssum += p1; agg = fmaf(h1, p1, agg);
        ssum += p2; agg = fmaf(h2, p2, agg);
        ssum += p3; agg = fmaf(h3, p3, agg);
        ssum += p4; agg = fmaf(h4, p4, agg);
        ssum += p5; agg = fmaf(h5, p5, agg);
        ssum += p6; agg = fmaf(h6, p6, agg);
        ssum += p7; agg = fmaf(h7, p7, agg);
      }
      for (; k + 4 <= deg; k += 4) {
        int s0 = sls[wid][k],     s1 = sls[wid][k + 1];
        int s2 = sls[wid][k + 2], s3 = sls[wid][k + 3];
        float h0 = hin[(size_t)s0 * H + lane];
        float h1 = hin[(size_t)s1 * H + lane];
        float h2 = hin[(size_t)s2 * H + lane];
        float h3 = hin[(size_t)s3 * H + lane];
        float p0 = __expf(els[wid][k] - m);
        float p1 = __expf(els[wid][k + 1] - m);
        float p2 = __expf(els[wid][k + 2] - m);
        float p3 = __expf(els[wid][k + 3] - m);
        ssum += p0; agg = fmaf(h0, p0, agg);
        ssum += p1; agg = fmaf(h1, p1, agg);
        ssum += p2; agg = fmaf(h2, p2, agg);
        ssum += p3; agg = fmaf(h3, p3, agg);
      }
      for (; k < deg; ++k) {
        int sj = sls[wid][k];
        float hv = hin[(size_t)sj * H + lane];
        float p = __expf(els[wid][k] - m);
        ssum += p; agg = fmaf(hv, p, agg);
      }
    } else {
      for (int j = st + lane; j < en; j += 64) {
        int2 r = erec[j];
        float e = ed + esrc[r.x & 0xFFFFF] + er[(r.x >> 20) & 7];
        e = e > 0.f ? e : 0.2f * e;
        m = fmaxf(m, e + __int_as_float(r.y));
      }
      #pragma unroll
      for (int o = 32; o >= 1; o >>= 1) m = fmaxf(m, __shfl_xor(m, o));
      for (int j = st; j < en; ++j) {
        int2 r = erec[j];
        int sj = r.x & 0xFFFFF;
        float e = ed + esrc[sj] + er[(r.x >> 20) & 7];
        e = e > 0.f ? e : 0.2f * e;
        e += __int_as_float(r.y);
        float p = __expf(e - m);
        ssum += p;
        agg = fmaf(hin[(size_t)sj * H + lane], p, agg);
      }
    }

    aggs[wid][lane] = (deg > 0) ? agg / ssum : 0.f;
    // epilogue GEMM: out = agg @ Wmsg (wave-internal LDS, no barrier needed)
    float out = 0.f;
    const float4* ag4 = (const float4*)aggs[wid];
    #pragma unroll
    for (int kq = 0; kq < H / 4; ++kq) {
      float4 a = ag4[kq];
      int k = kq * 4;
      out = fmaf(a.x, Ws[(k + 0) * H + lane], out);
      out = fmaf(a.y, Ws[(k + 1) * H + lane], out);
      out = fmaf(a.z, Ws[(k + 2) * H + lane], out);
      out = fmaf(a.w, Ws[(k + 3) * H + lane], out);
    }
    out += bb;
    float v = hin[(size_t)w * H + lane] + fmaxf(out, 0.f);
    float mu = v;
    #pragma unroll
    for (int off = 32; off >= 1; off >>= 1) mu += __shfl_xor(mu, off);
    mu *= (1.f / 64.f);
    float dv = v - mu;
    float var = dv * dv;
    #pragma unroll
    for (int off = 32; off >= 1; off >>= 1) var += __shfl_xor(var, off);
    var *= (1.f / 64.f);
    float res = dv * rsqrtf(var + 1e-5f) * lg + lb;
    hout[(size_t)w * H + lane] = res;
    if (!last) {
      float vs = res * wsn, vd = res * wdn;
      #pragma unroll
      for (int o = 32; o >= 1; o >>= 1) {
        vs += __shfl_xor(vs, o);
        vd += __shfl_xor(vd, o);
      }
      if (lane == 0) { esrc_o[w] = vs; edst_o[w] = vd; }
    }
  }
}

extern "C" void kernel_launch(void* const* d_in, const int* in_sizes, int n_in,
                              void* d_out, int out_size, void* d_ws, size_t ws_size,
                              hipStream_t stream) {
  const float* x       = (const float*)d_in[0];
  const float* W_in    = (const float*)d_in[1];
  const float* b_in    = (const float*)d_in[2];
  const float* W_msg   = (const float*)d_in[3];
  const float* rel_emb = (const float*)d_in[4];
  const float* W_rp    = (const float*)d_in[5];
  const float* att     = (const float*)d_in[6];
  const float* bias    = (const float*)d_in[7];
  const float* ln_g    = (const float*)d_in[8];
  const float* ln_b    = (const float*)d_in[9];
  const float* ea      = (const float*)d_in[10];
  const int*   ei      = (const int*)d_in[11];
  const int*   et      = (const int*)d_in[12];

  int N = in_sizes[0] / IN_DIM;
  int E = in_sizes[12];
  int L = in_sizes[7] / H;
  int R = in_sizes[5] / (L * H);
  int nb = (N + SCAN_B - 1) / SCAN_B;

  int bshift = 9;
  while (((N + (1 << bshift) - 1) >> bshift) > MAXBUCK) bshift++;
  int nbuck = (N + (1 << bshift) - 1) >> bshift;
  int nwg = (E + CHUNK - 1) / CHUNK;
  int M = nbuck * nwg;
  int nb2 = (M + SCAN_B - 1) / SCAN_B;

  float* ws   = (float*)d_ws;
  float* h0   = ws;                          // N*H
  float* h1   = h0 + (size_t)N * H;          // N*H floats; staged overlays it
  int4* staged = (int4*)h1;                  // E int4
  size_t hElems = (size_t)N * H;
  size_t stagedElems = ((size_t)E * 4 + 3) & ~(size_t)3;
  size_t region2 = hElems > stagedElems ? hElems : stagedElems;
  int2*  erec  = (int2*)(h1 + region2);      // E
  float* esrcA = (float*)(erec + E);         // N
  float* edstA = esrcA + N;                  // N
  float* esrcB = edstA + N;                  // N
  float* edstB = esrcB + N;                  // N
  float* erel  = edstB + N;                  // L*NRELS
  float* wdst  = erel + (size_t)L * NRELS;   // L*H
  float* wsrc  = wdst + (size_t)L * H;       // L*H
  int* row    = (int*)(wsrc + (size_t)L * H); // N+1
  int* deg    = row + N + 1;                 // N
  int* inc    = deg + N;                     // N
  int* bsum   = inc + N;                     // nb
  int* counts = bsum + nb;                   // M
  int* cinc   = counts + M;                  // M
  int* woff   = cinc + M;                    // M
  int* bsum2  = woff + M;                    // nb2

  k_wvec<<<L, H, 0, stream>>>(W_msg, att, wdst, wsrc);

  int nb16 = (N + 15) / 16;
  k_input<<<nb16, 256, 0, stream>>>(x, W_in, b_in, wsrc, wdst, h0, esrcA, edstA, N);

  // binned two-pass scatter (bucket-sorted staging)
  k_bhist<<<nwg, 256, 0, stream>>>(ei, counts, E, nwg, nbuck, bshift);
  k_scan1<<<nb2, SCAN_B, 0, stream>>>(counts, cinc, bsum2, M);
  k_scan2<<<1, SCAN_B, 0, stream>>>(bsum2, nb2);
  k_scan3b<<<nb2, SCAN_B, 0, stream>>>(cinc, bsum2, counts, woff, M);
  k_binscat<<<nwg, 256, 0, stream>>>(ei, et, ea, woff, staged, E, nwg, nbuck, bshift);

  k_hist2<<<nbuck, 256, 0, stream>>>((const int*)staged, woff, deg, E, nwg, nbuck, bshift, N);
  k_scan1<<<nb, SCAN_B, 0, stream>>>(deg, inc, bsum, N);
  k_scan2<<<1, SCAN_B, 0, stream>>>(bsum, nb);
  k_scan3<<<nb, SCAN_B, 0, stream>>>(inc, bsum, deg, row, N);
  k_scat2<<<nbuck, 256, 0, stream>>>(staged, woff, row, erec, E, nwg, nbuck, bshift, N);

  k_rel<<<L, 512, 0, stream>>>(rel_emb, W_rp, att, erel, R);

  for (int l = 0; l < L; ++l) {
    int last = (l == L - 1);
    const float* hin  = (l & 1) ? h1 : h0;
    float* hout = last ? (float*)d_out : ((l & 1) ? h0 : h1);
    const float* esI = (l & 1) ? esrcB : esrcA;
    const float* edI = (l & 1) ? edstB : edstA;
    float* esO = (l & 1) ? esrcA : esrcB;
    float* edO = (l & 1) ? edstA : edstB;
    k_agg<<<nb16, 256, 0, stream>>>(row, erec, esI, edI,
                                    erel + (size_t)l * NRELS,
                                    W_msg + (size_t)l * H * H, hin,
                                    bias + (size_t)l * H,
                                    ln_g + (size_t)l * H,
                                    ln_b + (size_t)l * H,
                                    last ? wsrc : wsrc + (size_t)(l + 1) * H,
                                    last ? wdst : wdst + (size_t)(l + 1) * H,
                                    esO, edO, hout, N, last);
  }
}